// Round 15
// baseline (168.106 us; speedup 1.0000x reference)
//
#include <hip/hip_runtime.h>
#include <cmath>

#define NPIX 4096      // 64*64 pixels per image
#define NTOT 16384     // 4 * 4096
#define CIN  256

typedef __bf16 bf16x8 __attribute__((ext_vector_type(8)));
typedef float  f32x4  __attribute__((ext_vector_type(4)));
typedef unsigned short u16x8 __attribute__((ext_vector_type(8)));

static __device__ __forceinline__ unsigned short f2bf(float f) {
    unsigned u = __float_as_uint(f);
    unsigned r = (u + 0x7FFFu + ((u >> 16) & 1u)) >> 16;
    return (unsigned short)r;
}
static __device__ __forceinline__ float bf2f(unsigned short u) {
    return __uint_as_float((unsigned)u << 16);
}

// ---------------- channel-major fp32 [B][256][4096] -> pixel-major bf16 [B*4096][256] ----------------
__global__ __launch_bounds__(256) void k_transpose_bf(const float* __restrict__ src,
                                                      unsigned short* __restrict__ dst) {
    __shared__ float tile[64][65];
    int p0 = blockIdx.x * 64;          // pixel base
    int c0 = blockIdx.y * 64;          // channel base
    int b  = blockIdx.z;
    int t = threadIdx.x;
    int tp = t & 63, tg = t >> 6;      // tg 0..3
    const float* s = src + ((size_t)(b * 256 + c0) * 4096) + p0;
#pragma unroll
    for (int r = 0; r < 16; ++r) {
        int c = r * 4 + tg;
        tile[tp][c] = s[(size_t)c * 4096 + tp];
    }
    __syncthreads();
    unsigned short* d = dst + ((size_t)(b * 4096 + p0)) * 256 + c0;
#pragma unroll
    for (int r = 0; r < 16; ++r) {
        int pr = r * 4 + tg;
        d[(size_t)pr * 256 + tp] = f2bf(tile[pr][tp]);
    }
}

// ---------------- depthwise 3x3 conv on pixel-major bf16: DWB[p][c] = conv(FMB)[p][c] ----------------
__global__ __launch_bounds__(256) void k_dwconv_bf(const unsigned short* __restrict__ FMB,
                                                   const float* __restrict__ wdw,
                                                   unsigned short* __restrict__ DWB) {
    __shared__ float wl[2560];         // [256 c][10] (pad-10 to dodge bank conflicts)
    int t = threadIdx.x;
    for (int i = t; i < 2304; i += 256) wl[(i / 9) * 10 + (i % 9)] = wdw[i];
    __syncthreads();
    int idx = blockIdx.x * 256 + t;    // over NTOT * 32 (8 channels each)
    int cg = idx & 31, p = idx >> 5;
    int xy = p & 4095, x = xy >> 6, y = xy & 63;
    const unsigned short* base = FMB + (size_t)p * 256 + cg * 8;
    float s[8] = {0.f, 0.f, 0.f, 0.f, 0.f, 0.f, 0.f, 0.f};
#pragma unroll
    for (int dx = 0; dx < 3; ++dx) {
        int xx = x + dx - 1;
        if ((unsigned)xx >= 64u) continue;
#pragma unroll
        for (int dy = 0; dy < 3; ++dy) {
            int yy = y + dy - 1;
            if ((unsigned)yy >= 64u) continue;
            u16x8 v = *(const u16x8*)(base + ((dx - 1) * 64 + (dy - 1)) * 256);
#pragma unroll
            for (int d = 0; d < 8; ++d)
                s[d] += bf2f(v[d]) * wl[(cg * 8 + d) * 10 + dx * 3 + dy];
        }
    }
    uint4 w0;
    w0.x = (unsigned)f2bf(s[0]) | ((unsigned)f2bf(s[1]) << 16);
    w0.y = (unsigned)f2bf(s[2]) | ((unsigned)f2bf(s[3]) << 16);
    w0.z = (unsigned)f2bf(s[4]) | ((unsigned)f2bf(s[5]) << 16);
    w0.w = (unsigned)f2bf(s[6]) | ((unsigned)f2bf(s[7]) << 16);
    *(uint4*)(DWB + (size_t)p * 256 + cg * 8) = w0;
}

// ---------------- weights fp32 -> bf16 ----------------
// WQKV[2048][256] = w_lq | w_q | w_kv.  WPW[1024][256] = head-paired (k_h | v_h per 128 rows).
// WOUT[256][1024] = w_out.
__global__ __launch_bounds__(256) void k_convert_w(const float* __restrict__ w1, const float* __restrict__ w2,
                                                   const float* __restrict__ w3, const float* __restrict__ w4,
                                                   const float* __restrict__ w5,
                                                   unsigned short* __restrict__ dst) {
    int i = blockIdx.x * 256 + threadIdx.x;  // 0..1048575
    float v;
    if (i < 131072)       v = w1[i];
    else if (i < 262144)  v = w2[i - 131072];
    else if (i < 524288)  v = w3[i - 262144];
    else if (i < 786432) {
        int elem = i - 524288;
        int rp = elem >> 8, c = elem & 255;
        int h = rp >> 7, wi = rp & 127;
        int srow = (wi < 64) ? (h * 64 + wi) : (512 + h * 64 + (wi - 64));
        v = w4[srow * 256 + c];
    } else                v = w5[i - 786432];
    dst[i] = f2bf(v);
}

// ---------------- G1: QKV projection GEMM, K=256, 128x128 tiles, counted-vmcnt 2-deep ----------------
// A=FMB, B=WQKV, n0=by*128. TILE-MAJOR outputs (wave-contiguous 32KB stores per block):
// n0<512 -> LQBT[n0>>7][16384][128] with FUSED head-softmax (*0.125);
// n0>=512 -> CKV2T[(n0-512)>>7][16384][128] (q tiles 4..7 pre-scaled 0.125).
__global__ __launch_bounds__(256) void k_g1_gemm(const __bf16* __restrict__ A,
                                                 const __bf16* __restrict__ B,
                                                 unsigned short* __restrict__ LQBT,
                                                 unsigned short* __restrict__ CKV2T) {
    __shared__ __align__(16) __bf16 SMEM[32768];   // 64 KB: 2 tile-bufs x (A 8192 + B 8192 elems)
    const int K = 256;
    const int m0 = blockIdx.x * 128;
    const int n0 = blockIdx.y * 128;
    const int t = threadIdx.x;
    const int w = t >> 6, l = t & 63;
    const int wm = (w >> 1) * 64, wn = (w & 1) * 64;
    f32x4 acc[4][4];
#pragma unroll
    for (int i = 0; i < 4; ++i)
#pragma unroll
        for (int j = 0; j < 4; ++j) acc[i][j] = (f32x4){0.f, 0.f, 0.f, 0.f};

    const int lrow = l >> 3;
    const int lchunk = (l & 7) ^ lrow;        // source pre-swizzle; LDS[row][pc]=global[row][pc^(row&7)]
    auto STAGE = [&](int buf, int k0) {
#pragma unroll
        for (int r = 0; r < 4; ++r) {
            const int s = w + r * 4;
            const int row = s * 8 + lrow;
            const __bf16* ga = A + (size_t)(m0 + row) * K + (k0 + lchunk * 8);
            const __bf16* gb = B + (size_t)(n0 + row) * K + (k0 + lchunk * 8);
            __builtin_amdgcn_global_load_lds((const __attribute__((address_space(1))) void*)ga,
                                             (__attribute__((address_space(3))) void*)(SMEM + buf * 16384 + s * 512),
                                             16, 0, 0);
            __builtin_amdgcn_global_load_lds((const __attribute__((address_space(1))) void*)gb,
                                             (__attribute__((address_space(3))) void*)(SMEM + buf * 16384 + 8192 + s * 512),
                                             16, 0, 0);
        }
    };
    STAGE(0, 0);
    STAGE(1, 64);
#pragma unroll
    for (int it = 0; it < 4; ++it) {
        if (it < 3) { asm volatile("s_waitcnt vmcnt(8)" ::: "memory"); }
        else        { asm volatile("s_waitcnt vmcnt(0)" ::: "memory"); }
        __builtin_amdgcn_sched_barrier(0);
        __builtin_amdgcn_s_barrier();
        __builtin_amdgcn_sched_barrier(0);
        const __bf16* As = SMEM + (it & 1) * 16384;
        const __bf16* Bs = As + 8192;
#pragma unroll
        for (int ks = 0; ks < 2; ++ks) {
            bf16x8 af[4], bfr[4];
#pragma unroll
            for (int i = 0; i < 4; ++i) {
                const int arow = wm + i * 16 + (l & 15);
                const int ac = ((l >> 4) + ks * 4) ^ (l & 7);   // read-side swizzle
                af[i] = *(const bf16x8*)(As + arow * 64 + ac * 8);
                const int brow = wn + i * 16 + (l & 15);
                bfr[i] = *(const bf16x8*)(Bs + brow * 64 + ac * 8);
            }
#pragma unroll
            for (int i = 0; i < 4; ++i)
#pragma unroll
                for (int j = 0; j < 4; ++j)
                    acc[i][j] = __builtin_amdgcn_mfma_f32_16x16x32_bf16(af[i], bfr[j], acc[i][j], 0, 0, 0);
        }
        __builtin_amdgcn_sched_barrier(0);
        __builtin_amdgcn_s_barrier();     // all waves done reading buf (it&1) -> safe to restage
        __builtin_amdgcn_sched_barrier(0);
        if (it < 2) STAGE(it & 1, (it + 2) * 64);
    }

    // ---- epilogue: stage bf16 tile row-major (stride 136), write tile-major wave-contiguous ----
#pragma unroll
    for (int i = 0; i < 4; ++i) {
        const int prow = wm + i * 16 + (l >> 4) * 4;
#pragma unroll
        for (int j = 0; j < 4; ++j) {
            const int col = wn + j * 16 + (l & 15);
            const int cglob = n0 + col;
            const float sc = (cglob >= 512 && cglob < 1024) ? 0.125f : 1.f;  // q pre-scaled
#pragma unroll
            for (int q = 0; q < 4; ++q)
                *((unsigned short*)SMEM + (prow + q) * 136 + col) = f2bf(acc[i][j][q] * sc);
        }
    }
    __syncthreads();
    const int pix = t >> 1, half = t & 1;
    unsigned short* sp = (unsigned short*)SMEM + pix * 136 + half * 64;
    if (n0 < 512) {
        // fused lq softmax over this thread's (pixel, head) 64-value slice.
        float m = -1e30f;
#pragma unroll
        for (int r = 0; r < 8; ++r) {
            u16x8 v = *(const u16x8*)(sp + r * 8);
#pragma unroll
            for (int d = 0; d < 8; ++d) m = fmaxf(m, bf2f(v[d]));
        }
        float Z = 0.f;
#pragma unroll
        for (int r = 0; r < 8; ++r) {
            u16x8 v = *(const u16x8*)(sp + r * 8);
            u16x8 e;
#pragma unroll
            for (int d = 0; d < 8; ++d) {
                float ev = __expf(bf2f(v[d]) - m);
                Z += ev;
                e[d] = f2bf(ev);
            }
            *(u16x8*)(sp + r * 8) = e;    // thread-private slice, no hazard
        }
        float inv = 0.125f / Z;
        unsigned short* dst = LQBT + ((size_t)(n0 >> 7) << 21) + (size_t)m0 * 128 + t * 64;
#pragma unroll
        for (int r = 0; r < 8; ++r) {
            u16x8 e = *(const u16x8*)(sp + r * 8);
            float o[8];
#pragma unroll
            for (int d = 0; d < 8; ++d) o[d] = bf2f(e[d]) * inv;
            uint4 wv;
            wv.x = (unsigned)f2bf(o[0]) | ((unsigned)f2bf(o[1]) << 16);
            wv.y = (unsigned)f2bf(o[2]) | ((unsigned)f2bf(o[3]) << 16);
            wv.z = (unsigned)f2bf(o[4]) | ((unsigned)f2bf(o[5]) << 16);
            wv.w = (unsigned)f2bf(o[6]) | ((unsigned)f2bf(o[7]) << 16);
            *(uint4*)(dst + r * 8) = wv;
        }
    } else {
        unsigned short* dptr = CKV2T + ((size_t)((n0 - 512) >> 7) << 21) + (size_t)m0 * 128 + t * 64;
#pragma unroll
        for (int r = 0; r < 8; ++r)
            *(u16x8*)(dptr + r * 8) = *(const u16x8*)(sp + r * 8);
    }
}

// ---------------- G2: pointwise GEMM + fused ctx partial, K=256, 128x128 tiles ----------------
__global__ __launch_bounds__(256) void k_g2_gemm(const __bf16* __restrict__ A,
                                                 const __bf16* __restrict__ B,
                                                 float* __restrict__ PART,
                                                 float* __restrict__ S) {
    __shared__ __align__(16) __bf16 SMEM[32768];   // 64 KB
    const int K = 256;
    const int m0 = blockIdx.x * 128;
    const int n0 = blockIdx.y * 128;
    const int t = threadIdx.x;
    const int w = t >> 6, l = t & 63;
    const int wm = (w >> 1) * 64, wn = (w & 1) * 64;
    f32x4 acc[4][4];
#pragma unroll
    for (int i = 0; i < 4; ++i)
#pragma unroll
        for (int j = 0; j < 4; ++j) acc[i][j] = (f32x4){0.f, 0.f, 0.f, 0.f};

    const int lrow = l >> 3;
    const int lchunk = (l & 7) ^ lrow;
    auto STAGE = [&](int buf, int k0) {
#pragma unroll
        for (int r = 0; r < 4; ++r) {
            const int s = w + r * 4;
            const int row = s * 8 + lrow;
            const __bf16* ga = A + (size_t)(m0 + row) * K + (k0 + lchunk * 8);
            const __bf16* gb = B + (size_t)(n0 + row) * K + (k0 + lchunk * 8);
            __builtin_amdgcn_global_load_lds((const __attribute__((address_space(1))) void*)ga,
                                             (__attribute__((address_space(3))) void*)(SMEM + buf * 16384 + s * 512),
                                             16, 0, 0);
            __builtin_amdgcn_global_load_lds((const __attribute__((address_space(1))) void*)gb,
                                             (__attribute__((address_space(3))) void*)(SMEM + buf * 16384 + 8192 + s * 512),
                                             16, 0, 0);
        }
    };
    STAGE(0, 0);
    STAGE(1, 64);
#pragma unroll
    for (int it = 0; it < 4; ++it) {
        if (it < 3) { asm volatile("s_waitcnt vmcnt(8)" ::: "memory"); }
        else        { asm volatile("s_waitcnt vmcnt(0)" ::: "memory"); }
        __builtin_amdgcn_sched_barrier(0);
        __builtin_amdgcn_s_barrier();
        __builtin_amdgcn_sched_barrier(0);
        const __bf16* As = SMEM + (it & 1) * 16384;
        const __bf16* Bs = As + 8192;
#pragma unroll
        for (int ks = 0; ks < 2; ++ks) {
            bf16x8 af[4], bfr[4];
#pragma unroll
            for (int i = 0; i < 4; ++i) {
                const int arow = wm + i * 16 + (l & 15);
                const int ac = ((l >> 4) + ks * 4) ^ (l & 7);
                af[i] = *(const bf16x8*)(As + arow * 64 + ac * 8);
                const int brow = wn + i * 16 + (l & 15);
                bfr[i] = *(const bf16x8*)(Bs + brow * 64 + ac * 8);
            }
#pragma unroll
            for (int i = 0; i < 4; ++i)
#pragma unroll
                for (int j = 0; j < 4; ++j)
                    acc[i][j] = __builtin_amdgcn_mfma_f32_16x16x32_bf16(af[i], bfr[j], acc[i][j], 0, 0, 0);
        }
        __builtin_amdgcn_sched_barrier(0);
        __builtin_amdgcn_s_barrier();
        __builtin_amdgcn_sched_barrier(0);
        if (it < 2) STAGE(it & 1, (it + 2) * 64);
    }

    // ---- fused ctx partial: stage [exp(k)|v] col-major ST[col][130], ctx_part = exp(K)^T V ----
    unsigned short* ST = (unsigned short*)SMEM;   // 128*130 shorts = 33.3 KB (aliases tile bufs)
#pragma unroll
    for (int i = 0; i < 4; ++i) {
        const int prow = wm + i * 16 + (l >> 4) * 4;
#pragma unroll
        for (int j = 0; j < 4; ++j) {
            const int col = wn + j * 16 + (l & 15);
#pragma unroll
            for (int q = 0; q < 4; ++q) {
                float v = acc[i][j][q];
                ST[col * 130 + prow + q] = f2bf(col < 64 ? __expf(v) : v);
            }
        }
    }
    __syncthreads();
    const int h  = blockIdx.y;            // head
    const int bh = (m0 >> 12) * 8 + h;
    const int dm = (w >> 1) * 32, en = (w & 1) * 32;
    f32x4 c2[2][2];
    f32x4 s2[2];
#pragma unroll
    for (int i = 0; i < 2; ++i) {
        s2[i] = (f32x4){0.f, 0.f, 0.f, 0.f};
#pragma unroll
        for (int j = 0; j < 2; ++j) c2[i][j] = (f32x4){0.f, 0.f, 0.f, 0.f};
    }
    bf16x8 ones;
#pragma unroll
    for (int d = 0; d < 8; ++d) ones[d] = (__bf16)1.0f;
#pragma unroll
    for (int kp = 0; kp < 4; ++kp) {      // 4 chunks of 32 pixels
        bf16x8 af2[2], bv2[2];
#pragma unroll
        for (int i = 0; i < 2; ++i) {
            const int drow = dm + i * 16 + (l & 15);          // d col (0..63)
            af2[i] = *(const bf16x8*)(ST + drow * 130 + kp * 32 + (l >> 4) * 8);
            const int erow = 64 + en + i * 16 + (l & 15);     // v col (64..127)
            bv2[i] = *(const bf16x8*)(ST + erow * 130 + kp * 32 + (l >> 4) * 8);
        }
#pragma unroll
        for (int i = 0; i < 2; ++i)
#pragma unroll
            for (int j = 0; j < 2; ++j)
                c2[i][j] = __builtin_amdgcn_mfma_f32_16x16x32_bf16(af2[i], bv2[j], c2[i][j], 0, 0, 0);
        if ((w & 1) == 0)
#pragma unroll
            for (int i = 0; i < 2; ++i)
                s2[i] = __builtin_amdgcn_mfma_f32_16x16x32_bf16(af2[i], ones, s2[i], 0, 0, 0);
    }
    // clean raw-layout partial store (thread-linear, fully coalesced); decode happens in ctxnorm
    float* pp = PART + ((size_t)((m0 >> 7) * 8 + h)) * 4096 + t * 16;
#pragma unroll
    for (int i = 0; i < 2; ++i)
#pragma unroll
        for (int j = 0; j < 2; ++j)
            *(f32x4*)(pp + (i * 2 + j) * 4) = c2[i][j];
    if ((w & 1) == 0 && (l & 15) == 0) {  // tiny S atomics: 64 per block
#pragma unroll
        for (int i = 0; i < 2; ++i)
#pragma unroll
            for (int q = 0; q < 4; ++q)
                atomicAdd(&S[bh * 64 + dm + i * 16 + (l >> 4) * 4 + q], s2[i][q]);
    }
}

// ---------------- ctx reduce+normalize: CTXB[bh][e][d] = sum_slots PART / S ----------------
__global__ __launch_bounds__(256) void k_ctxnorm(const float* __restrict__ PART,
                                                 const float* __restrict__ S,
                                                 unsigned short* __restrict__ ctxb) {
    __shared__ float SUM[1024];
    __shared__ float sinv[32];
    const int bh = blockIdx.x, wq = blockIdx.y;
    const int b = bh >> 3, h = bh & 7;
    const int t = threadIdx.x;
    const int bd = (wq >> 1) * 32, be = (wq & 1) * 32;
#pragma unroll
    for (int r = 0; r < 4; ++r) {
        const int kl = t + 256 * r;
        const float* src = PART + (size_t)((b * 32) * 8 + h) * 4096 + wq * 1024 + kl;
        float s = 0.f;
#pragma unroll
        for (int mi = 0; mi < 32; ++mi)
            s += src[(size_t)mi * 8 * 4096];
        SUM[kl] = s;
    }
    if (t < 32) sinv[t] = 1.f / S[bh * 64 + bd + t];
    __syncthreads();
#pragma unroll
    for (int r = 0; r < 4; ++r) {
        const int idx = t + 256 * r;
        const int dd = idx & 31, ee = idx >> 5;
        const int d = bd + dd, e = be + ee;
        const int l2 = (((d >> 2) & 3) << 4) | (e & 15);
        const int i2 = (d >> 4) & 1, j2 = (e >> 4) & 1, q = d & 3;
        const int kl = l2 * 16 + (i2 * 2 + j2) * 4 + q;
        ctxb[(size_t)bh * 4096 + e * 64 + d] = f2bf(SUM[kl] * sinv[dd]);
    }
}

// ---------------- final projection GEMM, 64x128 tiles, K=1024, counted-vmcnt 2-deep ----------------
__global__ __launch_bounds__(256) void k_out_gemm(const __bf16* __restrict__ A,    // CATB [M][1024]
                                                  const __bf16* __restrict__ B,    // WOUT [256][1024]
                                                  float* __restrict__ C,
                                                  const float* __restrict__ bias) {
    __shared__ __align__(16) __bf16 SMEM[24576];   // 48 KB: 2 bufs x (A 4096 + B 8192 elems)
    const int K = 1024;
    const int m0 = blockIdx.x * 64, n0 = blockIdx.y * 128;
    const int t = threadIdx.x;
    const int w = t >> 6, l = t & 63;
    const int wm = (w >> 1) * 32, wn = (w & 1) * 64;
    f32x4 acc[2][4];
#pragma unroll
    for (int i = 0; i < 2; ++i)
#pragma unroll
        for (int j = 0; j < 4; ++j) acc[i][j] = (f32x4){0.f, 0.f, 0.f, 0.f};

    const int lrow = l >> 3;
    const int lchunk = (l & 7) ^ lrow;
    auto STAGE = [&](int buf, int k0) {
        __bf16* As = SMEM + buf * 12288;
        __bf16* Bs = As + 4096;
#pragma unroll
        for (int r = 0; r < 2; ++r) {         // A: 8 stripes (64 rows)
            const int s = w + r * 4;
            const int row = s * 8 + lrow;
            const __bf16* ga = A + (size_t)(m0 + row) * K + (k0 + lchunk * 8);
            __builtin_amdgcn_global_load_lds((const __attribute__((address_space(1))) void*)ga,
                                             (__attribute__((address_space(3))) void*)(As + s * 512),
                                             16, 0, 0);
        }
#pragma unroll
        for (int r = 0; r < 4; ++r) {         // B: 16 stripes (128 rows)
            const int s = w + r * 4;
            const int row = s * 8 + lrow;
            const __bf16* gb = B + (size_t)(n0 + row) * K + (k0 + lchunk * 8);
            __builtin_amdgcn_global_load_lds((const __attribute__((address_space(1))) void*)gb,
                                             (__attribute__((address_space(3))) void*)(Bs + s * 512),
                                             16, 0, 0);
        }
    };

    STAGE(0, 0);
    STAGE(1, 64);
    for (int it = 0; it < 16; ++it) {
        if (it < 15) { asm volatile("s_waitcnt vmcnt(6)" ::: "memory"); }
        else         { asm volatile("s_waitcnt vmcnt(0)" ::: "memory"); }
        __builtin_amdgcn_sched_barrier(0);
        __builtin_amdgcn_s_barrier();
        __builtin_amdgcn_sched_barrier(0);
        const __bf16* As = SMEM + (it & 1) * 12288;
        const __bf16* Bs = As + 4096;
#pragma unroll
        for (int ks = 0; ks < 2; ++ks) {
            const int ac = ((l >> 4) + ks * 4) ^ (l & 7);
            bf16x8 af[2], bfr[4];
#pragma unroll
            for (int i = 0; i < 2; ++i) {
                const int arow = wm + i * 16 + (l & 15);
                af[i] = *(const bf16x8*)(As + arow * 64 + ac * 8);
            }
#pragma unroll
            for (int j = 0; j < 4; ++j) {
                const int brow = wn + j * 16 + (l & 15);
                bfr[j] = *(const bf16x8*)(Bs + brow * 64 + ac * 8);
            }
#pragma unroll
            for (int i = 0; i < 2; ++i)
#pragma unroll
                for (int j = 0; j < 4; ++j)
                    acc[i][j] = __builtin_amdgcn_mfma_f32_16x16x32_bf16(af[i], bfr[j], acc[i][j], 0, 0, 0);
        }
        __builtin_amdgcn_sched_barrier(0);
        __builtin_amdgcn_s_barrier();
        __builtin_amdgcn_sched_barrier(0);
        if (it < 14) STAGE(it & 1, (it + 2) * 64);
    }
    const int b = m0 >> 12;
#pragma unroll
    for (int j = 0; j < 4; ++j) {
        const int col = n0 + wn + j * 16 + (l & 15);
        const float bv = bias[col];
        float* obase = C + ((size_t)(b * 256 + col) << 12);
#pragma unroll
        for (int i = 0; i < 2; ++i) {
            const int rb = (m0 & 4095) + wm + i * 16 + (l >> 4) * 4;
            f32x4 v = acc[i][j];
            v[0] += bv; v[1] += bv; v[2] += bv; v[3] += bv;
            *(f32x4*)(obase + rb) = v;
        }
    }
}

// ---------------- fused: lin_out (MFMA+GELU) and local 3x3 window attention -> CATB ----------------
// blocks [0,1024): lin path (p0=(bid&127)*128, h=bid>>7); blocks [1024,5120): local path.
// LQBT[4][16384][128]: head h at tile h>>1, col (h&1)*64.
// CKV2T[12][16384][128]: q tiles 0..3, k tiles 4..7, v tiles 8..11; head h -> tile base h>>1.
__global__ __launch_bounds__(256) void k_linlocal(const __bf16* __restrict__ LQBT,
                                                  const __bf16* __restrict__ ctxb,
                                                  const unsigned short* __restrict__ CKV,
                                                  unsigned short* __restrict__ CAT) {
    const int bid = blockIdx.x;
    const int t = threadIdx.x;
    if (bid < 1024) {
        const int p0 = (bid & 127) * 128;
        const int h  = bid >> 7;
        const int b  = p0 >> 12;
        const int w = t >> 6, l = t & 63;
        const int wm = w * 32;
        const __bf16* Bm = ctxb + (size_t)(b * 8 + h) * 4096;
        const __bf16* Ah = LQBT + ((size_t)(h >> 1) << 21) + (h & 1) * 64;
        f32x4 acc[2][4];
#pragma unroll
        for (int i = 0; i < 2; ++i)
#pragma unroll
            for (int j = 0; j < 4; ++j) acc[i][j] = (f32x4){0.f, 0.f, 0.f, 0.f};
#pragma unroll
        for (int ks = 0; ks < 2; ++ks) {
            const int c = (l >> 4) + ks * 4;
            bf16x8 af[2], bfr[4];
#pragma unroll
            for (int i = 0; i < 2; ++i) {
                const int row = p0 + wm + i * 16 + (l & 15);
                af[i] = *(const bf16x8*)(Ah + (size_t)row * 128 + c * 8);
            }
#pragma unroll
            for (int j = 0; j < 4; ++j) {
                const int erow = j * 16 + (l & 15);
                bfr[j] = *(const bf16x8*)(Bm + erow * 64 + c * 8);
            }
#pragma unroll
            for (int i = 0; i < 2; ++i)
#pragma unroll
                for (int j = 0; j < 4; ++j)
                    acc[i][j] = __builtin_amdgcn_mfma_f32_16x16x32_bf16(af[i], bfr[j], acc[i][j], 0, 0, 0);
        }
#pragma unroll
        for (int i = 0; i < 2; ++i) {
#pragma unroll
            for (int j = 0; j < 4; ++j) {
                const int e = j * 16 + (l & 15);
#pragma unroll
                for (int q = 0; q < 4; ++q) {
                    const int p = p0 + wm + i * 16 + (l >> 4) * 4 + q;
                    float x = acc[i][j][q];
                    float g = 0.5f * x * (1.f + erff(x * 0.70710678118654752f));
                    CAT[(size_t)p * 1024 + h * 64 + e] = f2bf(g);
                }
            }
        }
    } else {
        const int W = (bid - 1024) * 4 + (t >> 6);   // wave id 0..16383
        const int lane = t & 63;
        const int h = W & 7;
        const int G = W >> 3;                 // pixel-group 0..2047
        const int yg = G & 7, x = (G >> 3) & 63, b = G >> 9;
        const int lg = lane >> 3, c8 = lane & 7;
        const int y = (yg << 3) + lg;
        const int p = (b << 12) + (x << 6) + y;
        const unsigned short* Qp = CKV + ((size_t)(h >> 1) << 21) + (size_t)p * 128 + (h & 1) * 64 + c8 * 8;
        const unsigned short* Kp = Qp + ((size_t)4 << 21);
        const unsigned short* Vp = Qp + ((size_t)8 << 21);

        const bool okx[3] = {x > 0, true, x < 63};
        const bool oky[3] = {y > 0, true, y < 63};
        bool okn[9]; int ofs[9];
#pragma unroll
        for (int dx = 0; dx < 3; ++dx)
#pragma unroll
            for (int dy = 0; dy < 3; ++dy) {
                const int k = dx * 3 + dy;
                okn[k] = okx[dx] && oky[dy];
                ofs[k] = okn[k] ? ((dx - 1) * 64 + (dy - 1)) * 128 : 0;   // clamp to self if OOB
            }
        float qf[8];
        {
            u16x8 q8 = *(const u16x8*)Qp;
#pragma unroll
            for (int d = 0; d < 8; ++d) qf[d] = bf2f(q8[d]);
        }
        float sim[9];
#pragma unroll
        for (int k = 0; k < 9; ++k) {
            u16x8 k8 = *(const u16x8*)(Kp + ofs[k]);
            float s = 0.f;
#pragma unroll
            for (int d = 0; d < 8; ++d) s += qf[d] * bf2f(k8[d]);
            s = okn[k] ? s : 0.f;                 // OOB logit contributes exactly 0
            s += __shfl_xor(s, 1);
            s += __shfl_xor(s, 2);
            s += __shfl_xor(s, 4);                // octet all-reduce
            sim[k] = s;
        }
        float mx = sim[0];
#pragma unroll
        for (int k = 1; k < 9; ++k) mx = fmaxf(mx, sim[k]);
        float a[9], Z = 0.f;
#pragma unroll
        for (int k = 0; k < 9; ++k) { a[k] = __expf(sim[k] - mx); Z += a[k]; }
        float inv = 1.f / Z;
#pragma unroll
        for (int k = 0; k < 9; ++k) a[k] = okn[k] ? a[k] * inv : 0.f;   // OOB taps give 0 to PV
        float o[8] = {0.f, 0.f, 0.f, 0.f, 0.f, 0.f, 0.f, 0.f};
#pragma unroll
        for (int k = 0; k < 9; ++k) {
            u16x8 v8 = *(const u16x8*)(Vp + ofs[k]);
#pragma unroll
            for (int d = 0; d < 8; ++d) o[d] += a[k] * bf2f(v8[d]);
        }
        unsigned short* dst = CAT + (size_t)p * 1024 + 512 + h * 64 + c8 * 8;
        uint4 w0;
        w0.x = (unsigned)f2bf(o[0]) | ((unsigned)f2bf(o[1]) << 16);
        w0.y = (unsigned)f2bf(o[2]) | ((unsigned)f2bf(o[3]) << 16);
        w0.z = (unsigned)f2bf(o[4]) | ((unsigned)f2bf(o[5]) << 16);
        w0.w = (unsigned)f2bf(o[6]) | ((unsigned)f2bf(o[7]) << 16);
        *(uint4*)dst = w0;
    }
}

extern "C" void kernel_launch(void* const* d_in, const int* in_sizes, int n_in,
                              void* d_out, int out_size, void* d_ws, size_t ws_size,
                              hipStream_t stream) {
    const float* fmap  = (const float*)d_in[0];
    const float* w_lq  = (const float*)d_in[1];
    const float* w_dw  = (const float*)d_in[2];
    const float* w_pw  = (const float*)d_in[3];
    const float* w_q   = (const float*)d_in[4];
    const float* w_kv  = (const float*)d_in[5];
    const float* w_out = (const float*)d_in[6];
    const float* b_out = (const float*)d_in[7];
    float* out = (float*)d_out;

    // ---- workspace layout (~137 MB, all bf16 except PART/S) ----
    unsigned short* base = (unsigned short*)d_ws;
    unsigned short* CATB = base;                                // [16384][1024]
    unsigned short* FMB  = base + (size_t)NTOT * 1024;          // [16384][256]
    unsigned short* DWB  = FMB + (size_t)NTOT * 256;            // [16384][256]
    unsigned short* WB   = DWB + (size_t)NTOT * 256;            // weights
    unsigned short* WQKV = WB;                                  // [2048][256]
    unsigned short* WPW  = WB + 524288;                         // [1024][256] (head-paired)
    unsigned short* WOUT = WB + 786432;                         // [256][1024]
    unsigned short* CTXB = WB + 1048576;                        // [32][64][64]
    unsigned short* LQBT = CTXB + 131072;                       // [4][16384][128] tile-major
    unsigned short* CKV2T= LQBT + (size_t)NTOT * 512;           // [12][16384][128] tile-major
    float* PART = (float*)(CKV2T + (size_t)NTOT * 1536);        // [128*8][4096] fp32 raw partials
    float* S    = PART + (size_t)1024 * 4096;                   // [2048]

    k_transpose_bf<<<dim3(64, 4, 4), 256, 0, stream>>>(fmap, FMB);
    k_convert_w<<<4096, 256, 0, stream>>>(w_lq, w_q, w_kv, w_pw, w_out, WB);
    hipMemsetAsync(S, 0, 2048 * sizeof(float), stream);
    k_dwconv_bf<<<2048, 256, 0, stream>>>(FMB, w_dw, DWB);
    k_g2_gemm<<<dim3(128, 8), 256, 0, stream>>>((const __bf16*)DWB, (const __bf16*)WPW, PART, S);
    k_g1_gemm<<<dim3(128, 16), 256, 0, stream>>>((const __bf16*)FMB, (const __bf16*)WQKV, LQBT, CKV2T);
    k_ctxnorm<<<dim3(32, 4), 256, 0, stream>>>(PART, S, CTXB);
    k_linlocal<<<5120, 256, 0, stream>>>((const __bf16*)LQBT, (const __bf16*)CTXB, CKV2T, CATB);
    k_out_gemm<<<dim3(256, 2), 256, 0, stream>>>((const __bf16*)CATB, (const __bf16*)WOUT, out, b_out);
}

// Round 16
// 165.789 us; speedup vs baseline: 1.0140x; 1.0140x over previous
//
#include <hip/hip_runtime.h>
#include <cmath>

#define NPIX 4096      // 64*64 pixels per image
#define NTOT 16384     // 4 * 4096
#define CIN  256

typedef __bf16 bf16x8 __attribute__((ext_vector_type(8)));
typedef float  f32x4  __attribute__((ext_vector_type(4)));
typedef unsigned short u16x8 __attribute__((ext_vector_type(8)));

static __device__ __forceinline__ unsigned short f2bf(float f) {
    unsigned u = __float_as_uint(f);
    unsigned r = (u + 0x7FFFu + ((u >> 16) & 1u)) >> 16;
    return (unsigned short)r;
}
static __device__ __forceinline__ float bf2f(unsigned short u) {
    return __uint_as_float((unsigned)u << 16);
}

// ---------------- channel-major fp32 [B][256][4096] -> pixel-major bf16 [B*4096][256] ----------------
__global__ __launch_bounds__(256) void k_transpose_bf(const float* __restrict__ src,
                                                      unsigned short* __restrict__ dst) {
    __shared__ float tile[64][65];
    int p0 = blockIdx.x * 64;          // pixel base
    int c0 = blockIdx.y * 64;          // channel base
    int b  = blockIdx.z;
    int t = threadIdx.x;
    int tp = t & 63, tg = t >> 6;      // tg 0..3
    const float* s = src + ((size_t)(b * 256 + c0) * 4096) + p0;
#pragma unroll
    for (int r = 0; r < 16; ++r) {
        int c = r * 4 + tg;
        tile[tp][c] = s[(size_t)c * 4096 + tp];
    }
    __syncthreads();
    unsigned short* d = dst + ((size_t)(b * 4096 + p0)) * 256 + c0;
#pragma unroll
    for (int r = 0; r < 16; ++r) {
        int pr = r * 4 + tg;
        d[(size_t)pr * 256 + tp] = f2bf(tile[pr][tp]);
    }
}

// ---------------- depthwise 3x3 conv on pixel-major bf16: DWB[p][c] = conv(FMB)[p][c] ----------------
__global__ __launch_bounds__(256) void k_dwconv_bf(const unsigned short* __restrict__ FMB,
                                                   const float* __restrict__ wdw,
                                                   unsigned short* __restrict__ DWB) {
    __shared__ float wl[2560];         // [256 c][10] (pad-10 to dodge bank conflicts)
    int t = threadIdx.x;
    for (int i = t; i < 2304; i += 256) wl[(i / 9) * 10 + (i % 9)] = wdw[i];
    __syncthreads();
    int idx = blockIdx.x * 256 + t;    // over NTOT * 32 (8 channels each)
    int cg = idx & 31, p = idx >> 5;
    int xy = p & 4095, x = xy >> 6, y = xy & 63;
    const unsigned short* base = FMB + (size_t)p * 256 + cg * 8;
    float s[8] = {0.f, 0.f, 0.f, 0.f, 0.f, 0.f, 0.f, 0.f};
#pragma unroll
    for (int dx = 0; dx < 3; ++dx) {
        int xx = x + dx - 1;
        if ((unsigned)xx >= 64u) continue;
#pragma unroll
        for (int dy = 0; dy < 3; ++dy) {
            int yy = y + dy - 1;
            if ((unsigned)yy >= 64u) continue;
            u16x8 v = *(const u16x8*)(base + ((dx - 1) * 64 + (dy - 1)) * 256);
#pragma unroll
            for (int d = 0; d < 8; ++d)
                s[d] += bf2f(v[d]) * wl[(cg * 8 + d) * 10 + dx * 3 + dy];
        }
    }
    uint4 w0;
    w0.x = (unsigned)f2bf(s[0]) | ((unsigned)f2bf(s[1]) << 16);
    w0.y = (unsigned)f2bf(s[2]) | ((unsigned)f2bf(s[3]) << 16);
    w0.z = (unsigned)f2bf(s[4]) | ((unsigned)f2bf(s[5]) << 16);
    w0.w = (unsigned)f2bf(s[6]) | ((unsigned)f2bf(s[7]) << 16);
    *(uint4*)(DWB + (size_t)p * 256 + cg * 8) = w0;
}

// ---------------- weights fp32 -> bf16 ----------------
// WQKV[2048][256] = w_lq | w_q | w_kv.  WPW[1024][256] = head-paired (k_h | v_h per 128 rows).
// WOUT[256][1024] = w_out.
__global__ __launch_bounds__(256) void k_convert_w(const float* __restrict__ w1, const float* __restrict__ w2,
                                                   const float* __restrict__ w3, const float* __restrict__ w4,
                                                   const float* __restrict__ w5,
                                                   unsigned short* __restrict__ dst) {
    int i = blockIdx.x * 256 + threadIdx.x;  // 0..1048575
    float v;
    if (i < 131072)       v = w1[i];
    else if (i < 262144)  v = w2[i - 131072];
    else if (i < 524288)  v = w3[i - 262144];
    else if (i < 786432) {
        int elem = i - 524288;
        int rp = elem >> 8, c = elem & 255;
        int h = rp >> 7, wi = rp & 127;
        int srow = (wi < 64) ? (h * 64 + wi) : (512 + h * 64 + (wi - 64));
        v = w4[srow * 256 + c];
    } else                v = w5[i - 786432];
    dst[i] = f2bf(v);
}

// ---------------- G1: QKV projection GEMM, K=256, 128x128 tiles, counted-vmcnt 2-deep ----------------
// A=FMB, B=WQKV, n0=by*128.
// n0<512: FUSED lin branch: head-softmax in LDS -> lin = softmax(lq)/8 @ ctxb^T -> GELU -> CAT cols h*64.
// n0>=512: CKV2T[(n0-512)>>7][16384][128] tile-major (q tiles pre-scaled 0.125).
__global__ __launch_bounds__(256) void k_g1_gemm(const __bf16* __restrict__ A,
                                                 const __bf16* __restrict__ B,
                                                 const __bf16* __restrict__ ctxb,
                                                 unsigned short* __restrict__ CKV2T,
                                                 unsigned short* __restrict__ CAT) {
    __shared__ __align__(16) __bf16 SMEM[32768];   // 64 KB: 2 tile-bufs x (A 8192 + B 8192 elems)
    const int K = 256;
    const int m0 = blockIdx.x * 128;
    const int n0 = blockIdx.y * 128;
    const int t = threadIdx.x;
    const int w = t >> 6, l = t & 63;
    const int wm = (w >> 1) * 64, wn = (w & 1) * 64;
    f32x4 acc[4][4];
#pragma unroll
    for (int i = 0; i < 4; ++i)
#pragma unroll
        for (int j = 0; j < 4; ++j) acc[i][j] = (f32x4){0.f, 0.f, 0.f, 0.f};

    const int lrow = l >> 3;
    const int lchunk = (l & 7) ^ lrow;        // source pre-swizzle; LDS[row][pc]=global[row][pc^(row&7)]
    auto STAGE = [&](int buf, int k0) {
#pragma unroll
        for (int r = 0; r < 4; ++r) {
            const int s = w + r * 4;
            const int row = s * 8 + lrow;
            const __bf16* ga = A + (size_t)(m0 + row) * K + (k0 + lchunk * 8);
            const __bf16* gb = B + (size_t)(n0 + row) * K + (k0 + lchunk * 8);
            __builtin_amdgcn_global_load_lds((const __attribute__((address_space(1))) void*)ga,
                                             (__attribute__((address_space(3))) void*)(SMEM + buf * 16384 + s * 512),
                                             16, 0, 0);
            __builtin_amdgcn_global_load_lds((const __attribute__((address_space(1))) void*)gb,
                                             (__attribute__((address_space(3))) void*)(SMEM + buf * 16384 + 8192 + s * 512),
                                             16, 0, 0);
        }
    };
    STAGE(0, 0);
    STAGE(1, 64);
#pragma unroll
    for (int it = 0; it < 4; ++it) {
        if (it < 3) { asm volatile("s_waitcnt vmcnt(8)" ::: "memory"); }
        else        { asm volatile("s_waitcnt vmcnt(0)" ::: "memory"); }
        __builtin_amdgcn_sched_barrier(0);
        __builtin_amdgcn_s_barrier();
        __builtin_amdgcn_sched_barrier(0);
        const __bf16* As = SMEM + (it & 1) * 16384;
        const __bf16* Bs = As + 8192;
#pragma unroll
        for (int ks = 0; ks < 2; ++ks) {
            bf16x8 af[4], bfr[4];
#pragma unroll
            for (int i = 0; i < 4; ++i) {
                const int arow = wm + i * 16 + (l & 15);
                const int ac = ((l >> 4) + ks * 4) ^ (l & 7);   // read-side swizzle
                af[i] = *(const bf16x8*)(As + arow * 64 + ac * 8);
                const int brow = wn + i * 16 + (l & 15);
                bfr[i] = *(const bf16x8*)(Bs + brow * 64 + ac * 8);
            }
#pragma unroll
            for (int i = 0; i < 4; ++i)
#pragma unroll
                for (int j = 0; j < 4; ++j)
                    acc[i][j] = __builtin_amdgcn_mfma_f32_16x16x32_bf16(af[i], bfr[j], acc[i][j], 0, 0, 0);
        }
        __builtin_amdgcn_sched_barrier(0);
        __builtin_amdgcn_s_barrier();     // all waves done reading buf (it&1) -> safe to restage
        __builtin_amdgcn_sched_barrier(0);
        if (it < 2) STAGE(it & 1, (it + 2) * 64);
    }

    // ---- stage bf16 tile row-major (stride 136) ----
    unsigned short* SU = (unsigned short*)SMEM;
#pragma unroll
    for (int i = 0; i < 4; ++i) {
        const int prow = wm + i * 16 + (l >> 4) * 4;
#pragma unroll
        for (int j = 0; j < 4; ++j) {
            const int col = wn + j * 16 + (l & 15);
            const int cglob = n0 + col;
            const float sc = (cglob >= 512 && cglob < 1024) ? 0.125f : 1.f;  // q pre-scaled
#pragma unroll
            for (int q = 0; q < 4; ++q)
                SU[(prow + q) * 136 + col] = f2bf(acc[i][j][q] * sc);
        }
    }
    __syncthreads();
    if (n0 < 512) {
        // ---- fused lin branch ----
        // (a) per-(pixel,head) softmax in the thread's 64-value slice; write normalized bf16 back.
        const int pix = t >> 1, half = t & 1;
        unsigned short* sp = SU + pix * 136 + half * 64;
        float m = -1e30f;
#pragma unroll
        for (int r = 0; r < 8; ++r) {
            u16x8 v = *(const u16x8*)(sp + r * 8);
#pragma unroll
            for (int d = 0; d < 8; ++d) m = fmaxf(m, bf2f(v[d]));
        }
        float Z = 0.f;
#pragma unroll
        for (int r = 0; r < 8; ++r) {
            u16x8 v = *(const u16x8*)(sp + r * 8);
            u16x8 e;
#pragma unroll
            for (int d = 0; d < 8; ++d) {
                float ev = __expf(bf2f(v[d]) - m);
                Z += ev;
                e[d] = f2bf(ev);
            }
            *(u16x8*)(sp + r * 8) = e;    // thread-private slice
        }
        float inv = 0.125f / Z;
#pragma unroll
        for (int r = 0; r < 8; ++r) {
            u16x8 e = *(const u16x8*)(sp + r * 8);
#pragma unroll
            for (int d = 0; d < 8; ++d) e[d] = f2bf(bf2f(e[d]) * inv);
            *(u16x8*)(sp + r * 8) = e;    // normalized bf16 lq
        }
        __syncthreads();
        // (b) per-head 64x64 GEMM vs ctxb + GELU -> CAT. wave w: head h2=w>>1, rows (w&1)*64.
        const int h2 = w >> 1;
        const int h  = (n0 >> 6) + h2;
        const int rb = (w & 1) * 64;
        const int bimg = m0 >> 12;
        const __bf16* Bm = ctxb + (size_t)(bimg * 8 + h) * 4096;
        f32x4 a2[4][4];
#pragma unroll
        for (int i = 0; i < 4; ++i)
#pragma unroll
            for (int j = 0; j < 4; ++j) a2[i][j] = (f32x4){0.f, 0.f, 0.f, 0.f};
#pragma unroll
        for (int ks = 0; ks < 2; ++ks) {
            const int c = (l >> 4) + ks * 4;
            bf16x8 af[4], bfr[4];
#pragma unroll
            for (int i = 0; i < 4; ++i) {
                const int arow = rb + i * 16 + (l & 15);
                af[i] = *(const bf16x8*)((const __bf16*)SU + arow * 136 + h2 * 64 + c * 8);
            }
#pragma unroll
            for (int j = 0; j < 4; ++j) {
                const int erow = j * 16 + (l & 15);
                bfr[j] = *(const bf16x8*)(Bm + erow * 64 + c * 8);
            }
#pragma unroll
            for (int i = 0; i < 4; ++i)
#pragma unroll
                for (int j = 0; j < 4; ++j)
                    a2[i][j] = __builtin_amdgcn_mfma_f32_16x16x32_bf16(af[i], bfr[j], a2[i][j], 0, 0, 0);
        }
#pragma unroll
        for (int i = 0; i < 4; ++i) {
#pragma unroll
            for (int j = 0; j < 4; ++j) {
                const int e = j * 16 + (l & 15);
#pragma unroll
                for (int q = 0; q < 4; ++q) {
                    const int p = m0 + rb + i * 16 + (l >> 4) * 4 + q;
                    float x = a2[i][j][q];
                    float g = 0.5f * x * (1.f + erff(x * 0.70710678118654752f));
                    CAT[(size_t)p * 1024 + h * 64 + e] = f2bf(g);
                }
            }
        }
    } else {
        const int pix = t >> 1, half = t & 1;
        const unsigned short* sp = SU + pix * 136 + half * 64;
        unsigned short* dptr = CKV2T + ((size_t)((n0 - 512) >> 7) << 21) + (size_t)m0 * 128 + t * 64;
#pragma unroll
        for (int r = 0; r < 8; ++r)
            *(u16x8*)(dptr + r * 8) = *(const u16x8*)(sp + r * 8);
    }
}

// ---------------- G2: pointwise GEMM + fused ctx partial, K=256, 128x128 tiles ----------------
__global__ __launch_bounds__(256) void k_g2_gemm(const __bf16* __restrict__ A,
                                                 const __bf16* __restrict__ B,
                                                 float* __restrict__ PART,
                                                 float* __restrict__ S) {
    __shared__ __align__(16) __bf16 SMEM[32768];   // 64 KB
    const int K = 256;
    const int m0 = blockIdx.x * 128;
    const int n0 = blockIdx.y * 128;
    const int t = threadIdx.x;
    const int w = t >> 6, l = t & 63;
    const int wm = (w >> 1) * 64, wn = (w & 1) * 64;
    f32x4 acc[4][4];
#pragma unroll
    for (int i = 0; i < 4; ++i)
#pragma unroll
        for (int j = 0; j < 4; ++j) acc[i][j] = (f32x4){0.f, 0.f, 0.f, 0.f};

    const int lrow = l >> 3;
    const int lchunk = (l & 7) ^ lrow;
    auto STAGE = [&](int buf, int k0) {
#pragma unroll
        for (int r = 0; r < 4; ++r) {
            const int s = w + r * 4;
            const int row = s * 8 + lrow;
            const __bf16* ga = A + (size_t)(m0 + row) * K + (k0 + lchunk * 8);
            const __bf16* gb = B + (size_t)(n0 + row) * K + (k0 + lchunk * 8);
            __builtin_amdgcn_global_load_lds((const __attribute__((address_space(1))) void*)ga,
                                             (__attribute__((address_space(3))) void*)(SMEM + buf * 16384 + s * 512),
                                             16, 0, 0);
            __builtin_amdgcn_global_load_lds((const __attribute__((address_space(1))) void*)gb,
                                             (__attribute__((address_space(3))) void*)(SMEM + buf * 16384 + 8192 + s * 512),
                                             16, 0, 0);
        }
    };
    STAGE(0, 0);
    STAGE(1, 64);
#pragma unroll
    for (int it = 0; it < 4; ++it) {
        if (it < 3) { asm volatile("s_waitcnt vmcnt(8)" ::: "memory"); }
        else        { asm volatile("s_waitcnt vmcnt(0)" ::: "memory"); }
        __builtin_amdgcn_sched_barrier(0);
        __builtin_amdgcn_s_barrier();
        __builtin_amdgcn_sched_barrier(0);
        const __bf16* As = SMEM + (it & 1) * 16384;
        const __bf16* Bs = As + 8192;
#pragma unroll
        for (int ks = 0; ks < 2; ++ks) {
            bf16x8 af[4], bfr[4];
#pragma unroll
            for (int i = 0; i < 4; ++i) {
                const int arow = wm + i * 16 + (l & 15);
                const int ac = ((l >> 4) + ks * 4) ^ (l & 7);
                af[i] = *(const bf16x8*)(As + arow * 64 + ac * 8);
                const int brow = wn + i * 16 + (l & 15);
                bfr[i] = *(const bf16x8*)(Bs + brow * 64 + ac * 8);
            }
#pragma unroll
            for (int i = 0; i < 4; ++i)
#pragma unroll
                for (int j = 0; j < 4; ++j)
                    acc[i][j] = __builtin_amdgcn_mfma_f32_16x16x32_bf16(af[i], bfr[j], acc[i][j], 0, 0, 0);
        }
        __builtin_amdgcn_sched_barrier(0);
        __builtin_amdgcn_s_barrier();
        __builtin_amdgcn_sched_barrier(0);
        if (it < 2) STAGE(it & 1, (it + 2) * 64);
    }

    // ---- fused ctx partial: stage [exp(k)|v] col-major ST[col][130], ctx_part = exp(K)^T V ----
    unsigned short* ST = (unsigned short*)SMEM;   // 128*130 shorts = 33.3 KB (aliases tile bufs)
#pragma unroll
    for (int i = 0; i < 4; ++i) {
        const int prow = wm + i * 16 + (l >> 4) * 4;
#pragma unroll
        for (int j = 0; j < 4; ++j) {
            const int col = wn + j * 16 + (l & 15);
#pragma unroll
            for (int q = 0; q < 4; ++q) {
                float v = acc[i][j][q];
                ST[col * 130 + prow + q] = f2bf(col < 64 ? __expf(v) : v);
            }
        }
    }
    __syncthreads();
    const int h  = blockIdx.y;            // head
    const int bh = (m0 >> 12) * 8 + h;
    const int dm = (w >> 1) * 32, en = (w & 1) * 32;
    f32x4 c2[2][2];
    f32x4 s2[2];
#pragma unroll
    for (int i = 0; i < 2; ++i) {
        s2[i] = (f32x4){0.f, 0.f, 0.f, 0.f};
#pragma unroll
        for (int j = 0; j < 2; ++j) c2[i][j] = (f32x4){0.f, 0.f, 0.f, 0.f};
    }
    bf16x8 ones;
#pragma unroll
    for (int d = 0; d < 8; ++d) ones[d] = (__bf16)1.0f;
#pragma unroll
    for (int kp = 0; kp < 4; ++kp) {      // 4 chunks of 32 pixels
        bf16x8 af2[2], bv2[2];
#pragma unroll
        for (int i = 0; i < 2; ++i) {
            const int drow = dm + i * 16 + (l & 15);          // d col (0..63)
            af2[i] = *(const bf16x8*)(ST + drow * 130 + kp * 32 + (l >> 4) * 8);
            const int erow = 64 + en + i * 16 + (l & 15);     // v col (64..127)
            bv2[i] = *(const bf16x8*)(ST + erow * 130 + kp * 32 + (l >> 4) * 8);
        }
#pragma unroll
        for (int i = 0; i < 2; ++i)
#pragma unroll
            for (int j = 0; j < 2; ++j)
                c2[i][j] = __builtin_amdgcn_mfma_f32_16x16x32_bf16(af2[i], bv2[j], c2[i][j], 0, 0, 0);
        if ((w & 1) == 0)
#pragma unroll
            for (int i = 0; i < 2; ++i)
                s2[i] = __builtin_amdgcn_mfma_f32_16x16x32_bf16(af2[i], ones, s2[i], 0, 0, 0);
    }
    // clean raw-layout partial store (thread-linear, fully coalesced); decode happens in ctxnorm
    float* pp = PART + ((size_t)((m0 >> 7) * 8 + h)) * 4096 + t * 16;
#pragma unroll
    for (int i = 0; i < 2; ++i)
#pragma unroll
        for (int j = 0; j < 2; ++j)
            *(f32x4*)(pp + (i * 2 + j) * 4) = c2[i][j];
    if ((w & 1) == 0 && (l & 15) == 0) {  // tiny S atomics: 64 per block
#pragma unroll
        for (int i = 0; i < 2; ++i)
#pragma unroll
            for (int q = 0; q < 4; ++q)
                atomicAdd(&S[bh * 64 + dm + i * 16 + (l >> 4) * 4 + q], s2[i][q]);
    }
}

// ---------------- ctx reduce+normalize: CTXB[bh][e][d] = sum_slots PART / S ----------------
__global__ __launch_bounds__(256) void k_ctxnorm(const float* __restrict__ PART,
                                                 const float* __restrict__ S,
                                                 unsigned short* __restrict__ ctxb) {
    __shared__ float SUM[1024];
    __shared__ float sinv[32];
    const int bh = blockIdx.x, wq = blockIdx.y;
    const int b = bh >> 3, h = bh & 7;
    const int t = threadIdx.x;
    const int bd = (wq >> 1) * 32, be = (wq & 1) * 32;
#pragma unroll
    for (int r = 0; r < 4; ++r) {
        const int kl = t + 256 * r;
        const float* src = PART + (size_t)((b * 32) * 8 + h) * 4096 + wq * 1024 + kl;
        float s = 0.f;
#pragma unroll
        for (int mi = 0; mi < 32; ++mi)
            s += src[(size_t)mi * 8 * 4096];
        SUM[kl] = s;
    }
    if (t < 32) sinv[t] = 1.f / S[bh * 64 + bd + t];
    __syncthreads();
#pragma unroll
    for (int r = 0; r < 4; ++r) {
        const int idx = t + 256 * r;
        const int dd = idx & 31, ee = idx >> 5;
        const int d = bd + dd, e = be + ee;
        const int l2 = (((d >> 2) & 3) << 4) | (e & 15);
        const int i2 = (d >> 4) & 1, j2 = (e >> 4) & 1, q = d & 3;
        const int kl = l2 * 16 + (i2 * 2 + j2) * 4 + q;
        ctxb[(size_t)bh * 4096 + e * 64 + d] = f2bf(SUM[kl] * sinv[dd]);
    }
}

// ---------------- final projection GEMM, 64x128 tiles, K=1024, counted-vmcnt 2-deep ----------------
__global__ __launch_bounds__(256) void k_out_gemm(const __bf16* __restrict__ A,    // CATB [M][1024]
                                                  const __bf16* __restrict__ B,    // WOUT [256][1024]
                                                  float* __restrict__ C,
                                                  const float* __restrict__ bias) {
    __shared__ __align__(16) __bf16 SMEM[24576];   // 48 KB: 2 bufs x (A 4096 + B 8192 elems)
    const int K = 1024;
    const int m0 = blockIdx.x * 64, n0 = blockIdx.y * 128;
    const int t = threadIdx.x;
    const int w = t >> 6, l = t & 63;
    const int wm = (w >> 1) * 32, wn = (w & 1) * 64;
    f32x4 acc[2][4];
#pragma unroll
    for (int i = 0; i < 2; ++i)
#pragma unroll
        for (int j = 0; j < 4; ++j) acc[i][j] = (f32x4){0.f, 0.f, 0.f, 0.f};

    const int lrow = l >> 3;
    const int lchunk = (l & 7) ^ lrow;
    auto STAGE = [&](int buf, int k0) {
        __bf16* As = SMEM + buf * 12288;
        __bf16* Bs = As + 4096;
#pragma unroll
        for (int r = 0; r < 2; ++r) {         // A: 8 stripes (64 rows)
            const int s = w + r * 4;
            const int row = s * 8 + lrow;
            const __bf16* ga = A + (size_t)(m0 + row) * K + (k0 + lchunk * 8);
            __builtin_amdgcn_global_load_lds((const __attribute__((address_space(1))) void*)ga,
                                             (__attribute__((address_space(3))) void*)(As + s * 512),
                                             16, 0, 0);
        }
#pragma unroll
        for (int r = 0; r < 4; ++r) {         // B: 16 stripes (128 rows)
            const int s = w + r * 4;
            const int row = s * 8 + lrow;
            const __bf16* gb = B + (size_t)(n0 + row) * K + (k0 + lchunk * 8);
            __builtin_amdgcn_global_load_lds((const __attribute__((address_space(1))) void*)gb,
                                             (__attribute__((address_space(3))) void*)(Bs + s * 512),
                                             16, 0, 0);
        }
    };

    STAGE(0, 0);
    STAGE(1, 64);
    for (int it = 0; it < 16; ++it) {
        if (it < 15) { asm volatile("s_waitcnt vmcnt(6)" ::: "memory"); }
        else         { asm volatile("s_waitcnt vmcnt(0)" ::: "memory"); }
        __builtin_amdgcn_sched_barrier(0);
        __builtin_amdgcn_s_barrier();
        __builtin_amdgcn_sched_barrier(0);
        const __bf16* As = SMEM + (it & 1) * 12288;
        const __bf16* Bs = As + 4096;
#pragma unroll
        for (int ks = 0; ks < 2; ++ks) {
            const int ac = ((l >> 4) + ks * 4) ^ (l & 7);
            bf16x8 af[2], bfr[4];
#pragma unroll
            for (int i = 0; i < 2; ++i) {
                const int arow = wm + i * 16 + (l & 15);
                af[i] = *(const bf16x8*)(As + arow * 64 + ac * 8);
            }
#pragma unroll
            for (int j = 0; j < 4; ++j) {
                const int brow = wn + j * 16 + (l & 15);
                bfr[j] = *(const bf16x8*)(Bs + brow * 64 + ac * 8);
            }
#pragma unroll
            for (int i = 0; i < 2; ++i)
#pragma unroll
                for (int j = 0; j < 4; ++j)
                    acc[i][j] = __builtin_amdgcn_mfma_f32_16x16x32_bf16(af[i], bfr[j], acc[i][j], 0, 0, 0);
        }
        __builtin_amdgcn_sched_barrier(0);
        __builtin_amdgcn_s_barrier();
        __builtin_amdgcn_sched_barrier(0);
        if (it < 14) STAGE(it & 1, (it + 2) * 64);
    }
    const int b = m0 >> 12;
#pragma unroll
    for (int j = 0; j < 4; ++j) {
        const int col = n0 + wn + j * 16 + (l & 15);
        const float bv = bias[col];
        float* obase = C + ((size_t)(b * 256 + col) << 12);
#pragma unroll
        for (int i = 0; i < 2; ++i) {
            const int rb = (m0 & 4095) + wm + i * 16 + (l >> 4) * 4;
            f32x4 v = acc[i][j];
            v[0] += bv; v[1] += bv; v[2] += bv; v[3] += bv;
            *(f32x4*)(obase + rb) = v;
        }
    }
}

// ---------------- local 3x3 window attention -> CATB cols 512..1023 ----------------
// Wave = 8 consecutive-y pixels x 1 head; lane = (pixel<<3)|channel-octet.
// CKV2T[12][16384][128]: q tiles 0..3, k tiles 4..7, v tiles 8..11; head h -> tile h>>1, col (h&1)*64.
__global__ __launch_bounds__(256) void k_local_attn(const unsigned short* __restrict__ CKV,
                                                    unsigned short* __restrict__ CAT) {
    const int W = blockIdx.x * 4 + (threadIdx.x >> 6);   // wave id 0..16383
    const int lane = threadIdx.x & 63;
    const int h = W & 7;
    const int G = W >> 3;                 // pixel-group 0..2047
    const int yg = G & 7, x = (G >> 3) & 63, b = G >> 9;
    const int lg = lane >> 3, c8 = lane & 7;
    const int y = (yg << 3) + lg;
    const int p = (b << 12) + (x << 6) + y;
    const unsigned short* Qp = CKV + ((size_t)(h >> 1) << 21) + (size_t)p * 128 + (h & 1) * 64 + c8 * 8;
    const unsigned short* Kp = Qp + ((size_t)4 << 21);
    const unsigned short* Vp = Qp + ((size_t)8 << 21);

    const bool okx[3] = {x > 0, true, x < 63};
    const bool oky[3] = {y > 0, true, y < 63};
    bool okn[9]; int ofs[9];
#pragma unroll
    for (int dx = 0; dx < 3; ++dx)
#pragma unroll
        for (int dy = 0; dy < 3; ++dy) {
            const int k = dx * 3 + dy;
            okn[k] = okx[dx] && oky[dy];
            ofs[k] = okn[k] ? ((dx - 1) * 64 + (dy - 1)) * 128 : 0;   // clamp to self if OOB
        }
    float qf[8];
    {
        u16x8 q8 = *(const u16x8*)Qp;
#pragma unroll
        for (int d = 0; d < 8; ++d) qf[d] = bf2f(q8[d]);
    }
    float sim[9];
#pragma unroll
    for (int k = 0; k < 9; ++k) {
        u16x8 k8 = *(const u16x8*)(Kp + ofs[k]);
        float s = 0.f;
#pragma unroll
        for (int d = 0; d < 8; ++d) s += qf[d] * bf2f(k8[d]);
        s = okn[k] ? s : 0.f;                 // OOB logit contributes exactly 0
        s += __shfl_xor(s, 1);
        s += __shfl_xor(s, 2);
        s += __shfl_xor(s, 4);                // octet all-reduce
        sim[k] = s;
    }
    float mx = sim[0];
#pragma unroll
    for (int k = 1; k < 9; ++k) mx = fmaxf(mx, sim[k]);
    float a[9], Z = 0.f;
#pragma unroll
    for (int k = 0; k < 9; ++k) { a[k] = __expf(sim[k] - mx); Z += a[k]; }
    float inv = 1.f / Z;
#pragma unroll
    for (int k = 0; k < 9; ++k) a[k] = okn[k] ? a[k] * inv : 0.f;   // OOB taps give 0 to PV
    float o[8] = {0.f, 0.f, 0.f, 0.f, 0.f, 0.f, 0.f, 0.f};
#pragma unroll
    for (int k = 0; k < 9; ++k) {
        u16x8 v8 = *(const u16x8*)(Vp + ofs[k]);
#pragma unroll
        for (int d = 0; d < 8; ++d) o[d] += a[k] * bf2f(v8[d]);
    }
    unsigned short* dst = CAT + (size_t)p * 1024 + 512 + h * 64 + c8 * 8;
    uint4 w0;
    w0.x = (unsigned)f2bf(o[0]) | ((unsigned)f2bf(o[1]) << 16);
    w0.y = (unsigned)f2bf(o[2]) | ((unsigned)f2bf(o[3]) << 16);
    w0.z = (unsigned)f2bf(o[4]) | ((unsigned)f2bf(o[5]) << 16);
    w0.w = (unsigned)f2bf(o[6]) | ((unsigned)f2bf(o[7]) << 16);
    *(uint4*)dst = w0;
}

extern "C" void kernel_launch(void* const* d_in, const int* in_sizes, int n_in,
                              void* d_out, int out_size, void* d_ws, size_t ws_size,
                              hipStream_t stream) {
    const float* fmap  = (const float*)d_in[0];
    const float* w_lq  = (const float*)d_in[1];
    const float* w_dw  = (const float*)d_in[2];
    const float* w_pw  = (const float*)d_in[3];
    const float* w_q   = (const float*)d_in[4];
    const float* w_kv  = (const float*)d_in[5];
    const float* w_out = (const float*)d_in[6];
    const float* b_out = (const float*)d_in[7];
    float* out = (float*)d_out;

    // ---- workspace layout (~121 MB) ----
    unsigned short* base = (unsigned short*)d_ws;
    unsigned short* CATB = base;                                // [16384][1024]
    unsigned short* FMB  = base + (size_t)NTOT * 1024;          // [16384][256]
    unsigned short* DWB  = FMB + (size_t)NTOT * 256;            // [16384][256]
    unsigned short* WB   = DWB + (size_t)NTOT * 256;            // weights
    unsigned short* WQKV = WB;                                  // [2048][256]
    unsigned short* WPW  = WB + 524288;                         // [1024][256] (head-paired)
    unsigned short* WOUT = WB + 786432;                         // [256][1024]
    unsigned short* CTXB = WB + 1048576;                        // [32][64][64]
    unsigned short* CKV2T= CTXB + 131072;                       // [12][16384][128] tile-major
    float* PART = (float*)(CKV2T + (size_t)NTOT * 1536);        // [128*8][4096] fp32 raw partials
    float* S    = PART + (size_t)1024 * 4096;                   // [2048]

    k_transpose_bf<<<dim3(64, 4, 4), 256, 0, stream>>>(fmap, FMB);
    k_convert_w<<<4096, 256, 0, stream>>>(w_lq, w_q, w_kv, w_pw, w_out, WB);
    hipMemsetAsync(S, 0, 2048 * sizeof(float), stream);
    k_dwconv_bf<<<2048, 256, 0, stream>>>(FMB, w_dw, DWB);
    k_g2_gemm<<<dim3(128, 8), 256, 0, stream>>>((const __bf16*)DWB, (const __bf16*)WPW, PART, S);
    k_ctxnorm<<<dim3(32, 4), 256, 0, stream>>>(PART, S, CTXB);
    k_g1_gemm<<<dim3(128, 16), 256, 0, stream>>>((const __bf16*)FMB, (const __bf16*)WQKV,
                                                 (const __bf16*)CTXB, CKV2T, CATB);
    k_local_attn<<<4096, 256, 0, stream>>>(CKV2T, CATB);
    k_out_gemm<<<dim3(256, 2), 256, 0, stream>>>((const __bf16*)CATB, (const __bf16*)WOUT, out, b_out);
}

// Round 17
// 164.902 us; speedup vs baseline: 1.0194x; 1.0054x over previous
//
#include <hip/hip_runtime.h>
#include <cmath>

#define NPIX 4096      // 64*64 pixels per image
#define NTOT 16384     // 4 * 4096
#define CIN  256

typedef __bf16 bf16x8 __attribute__((ext_vector_type(8)));
typedef float  f32x4  __attribute__((ext_vector_type(4)));
typedef unsigned short u16x8 __attribute__((ext_vector_type(8)));

static __device__ __forceinline__ unsigned short f2bf(float f) {
    unsigned u = __float_as_uint(f);
    unsigned r = (u + 0x7FFFu + ((u >> 16) & 1u)) >> 16;
    return (unsigned short)r;
}
static __device__ __forceinline__ float bf2f(unsigned short u) {
    return __uint_as_float((unsigned)u << 16);
}

// ---------------- channel-major fp32 [B][256][4096] -> pixel-major bf16 [B*4096][256] ----------------
__global__ __launch_bounds__(256) void k_transpose_bf(const float* __restrict__ src,
                                                      unsigned short* __restrict__ dst) {
    __shared__ float tile[64][65];
    int p0 = blockIdx.x * 64;          // pixel base
    int c0 = blockIdx.y * 64;          // channel base
    int b  = blockIdx.z;
    int t = threadIdx.x;
    int tp = t & 63, tg = t >> 6;      // tg 0..3
    const float* s = src + ((size_t)(b * 256 + c0) * 4096) + p0;
#pragma unroll
    for (int r = 0; r < 16; ++r) {
        int c = r * 4 + tg;
        tile[tp][c] = s[(size_t)c * 4096 + tp];
    }
    __syncthreads();
    unsigned short* d = dst + ((size_t)(b * 4096 + p0)) * 256 + c0;
#pragma unroll
    for (int r = 0; r < 16; ++r) {
        int pr = r * 4 + tg;
        d[(size_t)pr * 256 + tp] = f2bf(tile[pr][tp]);
    }
}

// ---------------- depthwise 3x3 conv on pixel-major bf16: DWB[p][c] = conv(FMB)[p][c] ----------------
__global__ __launch_bounds__(256) void k_dwconv_bf(const unsigned short* __restrict__ FMB,
                                                   const float* __restrict__ wdw,
                                                   unsigned short* __restrict__ DWB) {
    __shared__ float wl[2560];         // [256 c][10] (pad-10 to dodge bank conflicts)
    int t = threadIdx.x;
    for (int i = t; i < 2304; i += 256) wl[(i / 9) * 10 + (i % 9)] = wdw[i];
    __syncthreads();
    int idx = blockIdx.x * 256 + t;    // over NTOT * 32 (8 channels each)
    int cg = idx & 31, p = idx >> 5;
    int xy = p & 4095, x = xy >> 6, y = xy & 63;
    const unsigned short* base = FMB + (size_t)p * 256 + cg * 8;
    float s[8] = {0.f, 0.f, 0.f, 0.f, 0.f, 0.f, 0.f, 0.f};
#pragma unroll
    for (int dx = 0; dx < 3; ++dx) {
        int xx = x + dx - 1;
        if ((unsigned)xx >= 64u) continue;
#pragma unroll
        for (int dy = 0; dy < 3; ++dy) {
            int yy = y + dy - 1;
            if ((unsigned)yy >= 64u) continue;
            u16x8 v = *(const u16x8*)(base + ((dx - 1) * 64 + (dy - 1)) * 256);
#pragma unroll
            for (int d = 0; d < 8; ++d)
                s[d] += bf2f(v[d]) * wl[(cg * 8 + d) * 10 + dx * 3 + dy];
        }
    }
    uint4 w0;
    w0.x = (unsigned)f2bf(s[0]) | ((unsigned)f2bf(s[1]) << 16);
    w0.y = (unsigned)f2bf(s[2]) | ((unsigned)f2bf(s[3]) << 16);
    w0.z = (unsigned)f2bf(s[4]) | ((unsigned)f2bf(s[5]) << 16);
    w0.w = (unsigned)f2bf(s[6]) | ((unsigned)f2bf(s[7]) << 16);
    *(uint4*)(DWB + (size_t)p * 256 + cg * 8) = w0;
}

// ---------------- weights fp32 -> bf16 ----------------
// WQKV[2048][256] = w_lq | w_q | w_kv.  WPW[1024][256] = head-paired (k_h | v_h per 128 rows).
// WOUT[256][1024] = w_out.
__global__ __launch_bounds__(256) void k_convert_w(const float* __restrict__ w1, const float* __restrict__ w2,
                                                   const float* __restrict__ w3, const float* __restrict__ w4,
                                                   const float* __restrict__ w5,
                                                   unsigned short* __restrict__ dst) {
    int i = blockIdx.x * 256 + threadIdx.x;  // 0..1048575
    float v;
    if (i < 131072)       v = w1[i];
    else if (i < 262144)  v = w2[i - 131072];
    else if (i < 524288)  v = w3[i - 262144];
    else if (i < 786432) {
        int elem = i - 524288;
        int rp = elem >> 8, c = elem & 255;
        int h = rp >> 7, wi = rp & 127;
        int srow = (wi < 64) ? (h * 64 + wi) : (512 + h * 64 + (wi - 64));
        v = w4[srow * 256 + c];
    } else                v = w5[i - 786432];
    dst[i] = f2bf(v);
}

// ---------------- merged QKV GEMM, K=256, 128x128 tiles, counted-vmcnt 2-deep pipeline ----------------
// by<16: A=FMB, B=WQKV, n0=by*128. TILE-MAJOR outputs:
//   n0<512 -> LQBT[n0>>7][16384][128] with FUSED head-softmax (*0.125);
//   n0>=512 -> CKV2T[(n0-512)>>7][16384][128] (q tiles pre-scaled 0.125).
// by>=16: A=DWB, B=WPW(head-paired), h=by-16: fused ctx partial into PART + tiny S atomics.
__global__ __launch_bounds__(256) void k_qkv_gemm(const __bf16* __restrict__ FMB,
                                                  const __bf16* __restrict__ DWB,
                                                  const __bf16* __restrict__ WQKV,
                                                  const __bf16* __restrict__ WPW,
                                                  unsigned short* __restrict__ LQBT,
                                                  unsigned short* __restrict__ CKV2T,
                                                  float* __restrict__ PART,
                                                  float* __restrict__ S) {
    __shared__ __align__(16) __bf16 SMEM[32768];   // 64 KB: 2 tile-bufs x (A 8192 + B 8192 elems)
    const int K = 256;
    const int m0 = blockIdx.x * 128;
    const int by = blockIdx.y;
    const bool g2 = (by >= 16);
    const __bf16* A = g2 ? DWB : FMB;
    const __bf16* B = g2 ? WPW : WQKV;
    const int n0 = (g2 ? by - 16 : by) * 128;
    const int t = threadIdx.x;
    const int w = t >> 6, l = t & 63;
    const int wm = (w >> 1) * 64, wn = (w & 1) * 64;
    f32x4 acc[4][4];
#pragma unroll
    for (int i = 0; i < 4; ++i)
#pragma unroll
        for (int j = 0; j < 4; ++j) acc[i][j] = (f32x4){0.f, 0.f, 0.f, 0.f};

    const int lrow = l >> 3;
    const int lchunk = (l & 7) ^ lrow;        // source pre-swizzle; LDS[row][pc]=global[row][pc^(row&7)]
    auto STAGE = [&](int buf, int k0) {
#pragma unroll
        for (int r = 0; r < 4; ++r) {
            const int s = w + r * 4;
            const int row = s * 8 + lrow;
            const __bf16* ga = A + (size_t)(m0 + row) * K + (k0 + lchunk * 8);
            const __bf16* gb = B + (size_t)(n0 + row) * K + (k0 + lchunk * 8);
            __builtin_amdgcn_global_load_lds((const __attribute__((address_space(1))) void*)ga,
                                             (__attribute__((address_space(3))) void*)(SMEM + buf * 16384 + s * 512),
                                             16, 0, 0);
            __builtin_amdgcn_global_load_lds((const __attribute__((address_space(1))) void*)gb,
                                             (__attribute__((address_space(3))) void*)(SMEM + buf * 16384 + 8192 + s * 512),
                                             16, 0, 0);
        }
    };
    STAGE(0, 0);
    STAGE(1, 64);
#pragma unroll
    for (int it = 0; it < 4; ++it) {
        // counted wait: tile it's 8 loads done; tile it+1's 8 stay in flight (never drain mid-loop)
        if (it < 3) { asm volatile("s_waitcnt vmcnt(8)" ::: "memory"); }
        else        { asm volatile("s_waitcnt vmcnt(0)" ::: "memory"); }
        __builtin_amdgcn_sched_barrier(0);
        __builtin_amdgcn_s_barrier();
        __builtin_amdgcn_sched_barrier(0);
        const __bf16* As = SMEM + (it & 1) * 16384;
        const __bf16* Bs = As + 8192;
#pragma unroll
        for (int ks = 0; ks < 2; ++ks) {
            bf16x8 af[4], bfr[4];
#pragma unroll
            for (int i = 0; i < 4; ++i) {
                const int arow = wm + i * 16 + (l & 15);
                const int ac = ((l >> 4) + ks * 4) ^ (l & 7);   // read-side swizzle
                af[i] = *(const bf16x8*)(As + arow * 64 + ac * 8);
                const int brow = wn + i * 16 + (l & 15);
                bfr[i] = *(const bf16x8*)(Bs + brow * 64 + ac * 8);
            }
#pragma unroll
            for (int i = 0; i < 4; ++i)
#pragma unroll
                for (int j = 0; j < 4; ++j)
                    acc[i][j] = __builtin_amdgcn_mfma_f32_16x16x32_bf16(af[i], bfr[j], acc[i][j], 0, 0, 0);
        }
        __builtin_amdgcn_sched_barrier(0);
        __builtin_amdgcn_s_barrier();     // all waves done reading buf (it&1) -> safe to restage
        __builtin_amdgcn_sched_barrier(0);
        if (it < 2) STAGE(it & 1, (it + 2) * 64);
    }

    if (g2) {
        // ---- fused ctx partial: stage [exp(k)|v] col-major ST[col][130], ctx_part = exp(K)^T V ----
        unsigned short* ST = (unsigned short*)SMEM;   // 128*130 shorts = 33.3 KB (aliases tile bufs)
#pragma unroll
        for (int i = 0; i < 4; ++i) {
            const int prow = wm + i * 16 + (l >> 4) * 4;
#pragma unroll
            for (int j = 0; j < 4; ++j) {
                const int col = wn + j * 16 + (l & 15);
#pragma unroll
                for (int q = 0; q < 4; ++q) {
                    float v = acc[i][j][q];
                    ST[col * 130 + prow + q] = f2bf(col < 64 ? __expf(v) : v);
                }
            }
        }
        __syncthreads();
        const int h  = n0 >> 7;               // head
        const int bh = (m0 >> 12) * 8 + h;
        const int dm = (w >> 1) * 32, en = (w & 1) * 32;
        f32x4 c2[2][2];
        f32x4 s2[2];
#pragma unroll
        for (int i = 0; i < 2; ++i) {
            s2[i] = (f32x4){0.f, 0.f, 0.f, 0.f};
#pragma unroll
            for (int j = 0; j < 2; ++j) c2[i][j] = (f32x4){0.f, 0.f, 0.f, 0.f};
        }
        bf16x8 ones;
#pragma unroll
        for (int d = 0; d < 8; ++d) ones[d] = (__bf16)1.0f;
#pragma unroll
        for (int kp = 0; kp < 4; ++kp) {      // 4 chunks of 32 pixels
            bf16x8 af2[2], bv2[2];
#pragma unroll
            for (int i = 0; i < 2; ++i) {
                const int drow = dm + i * 16 + (l & 15);          // d col (0..63)
                af2[i] = *(const bf16x8*)(ST + drow * 130 + kp * 32 + (l >> 4) * 8);
                const int erow = 64 + en + i * 16 + (l & 15);     // v col (64..127)
                bv2[i] = *(const bf16x8*)(ST + erow * 130 + kp * 32 + (l >> 4) * 8);
            }
#pragma unroll
            for (int i = 0; i < 2; ++i)
#pragma unroll
                for (int j = 0; j < 2; ++j)
                    c2[i][j] = __builtin_amdgcn_mfma_f32_16x16x32_bf16(af2[i], bv2[j], c2[i][j], 0, 0, 0);
            if ((w & 1) == 0)
#pragma unroll
                for (int i = 0; i < 2; ++i)
                    s2[i] = __builtin_amdgcn_mfma_f32_16x16x32_bf16(af2[i], ones, s2[i], 0, 0, 0);
        }
        // clean raw-layout partial store (thread-linear, fully coalesced); decode happens in ctxnorm
        float* pp = PART + ((size_t)((m0 >> 7) * 8 + h)) * 4096 + t * 16;
#pragma unroll
        for (int i = 0; i < 2; ++i)
#pragma unroll
            for (int j = 0; j < 2; ++j)
                *(f32x4*)(pp + (i * 2 + j) * 4) = c2[i][j];
        if ((w & 1) == 0 && (l & 15) == 0) {  // tiny S atomics: 64 per block
#pragma unroll
            for (int i = 0; i < 2; ++i)
#pragma unroll
                for (int q = 0; q < 4; ++q)
                    atomicAdd(&S[bh * 64 + dm + i * 16 + (l >> 4) * 4 + q], s2[i][q]);
        }
        return;
    }

    // ---- g1 epilogue: stage bf16 tile row-major (stride 136), write tile-major wave-contiguous ----
    unsigned short* SU = (unsigned short*)SMEM;
#pragma unroll
    for (int i = 0; i < 4; ++i) {
        const int prow = wm + i * 16 + (l >> 4) * 4;
#pragma unroll
        for (int j = 0; j < 4; ++j) {
            const int col = wn + j * 16 + (l & 15);
            const int cglob = n0 + col;
            const float sc = (cglob >= 512 && cglob < 1024) ? 0.125f : 1.f;  // q pre-scaled
#pragma unroll
            for (int q = 0; q < 4; ++q)
                SU[(prow + q) * 136 + col] = f2bf(acc[i][j][q] * sc);
        }
    }
    __syncthreads();
    const int pix = t >> 1, half = t & 1;
    unsigned short* sp = SU + pix * 136 + half * 64;
    if (n0 < 512) {
        // fused lq softmax (single-expf writeback variant) over the (pixel, head) 64-value slice
        float m = -1e30f;
#pragma unroll
        for (int r = 0; r < 8; ++r) {
            u16x8 v = *(const u16x8*)(sp + r * 8);
#pragma unroll
            for (int d = 0; d < 8; ++d) m = fmaxf(m, bf2f(v[d]));
        }
        float Z = 0.f;
#pragma unroll
        for (int r = 0; r < 8; ++r) {
            u16x8 v = *(const u16x8*)(sp + r * 8);
            u16x8 e;
#pragma unroll
            for (int d = 0; d < 8; ++d) {
                float ev = __expf(bf2f(v[d]) - m);
                Z += ev;
                e[d] = f2bf(ev);
            }
            *(u16x8*)(sp + r * 8) = e;    // thread-private slice, no hazard
        }
        float inv = 0.125f / Z;
        unsigned short* dst = LQBT + ((size_t)(n0 >> 7) << 21) + (size_t)m0 * 128 + t * 64;
#pragma unroll
        for (int r = 0; r < 8; ++r) {
            u16x8 e = *(const u16x8*)(sp + r * 8);
            float o[8];
#pragma unroll
            for (int d = 0; d < 8; ++d) o[d] = bf2f(e[d]) * inv;
            uint4 wv;
            wv.x = (unsigned)f2bf(o[0]) | ((unsigned)f2bf(o[1]) << 16);
            wv.y = (unsigned)f2bf(o[2]) | ((unsigned)f2bf(o[3]) << 16);
            wv.z = (unsigned)f2bf(o[4]) | ((unsigned)f2bf(o[5]) << 16);
            wv.w = (unsigned)f2bf(o[6]) | ((unsigned)f2bf(o[7]) << 16);
            *(uint4*)(dst + r * 8) = wv;
        }
    } else {
        unsigned short* dptr = CKV2T + ((size_t)((n0 - 512) >> 7) << 21) + (size_t)m0 * 128 + t * 64;
#pragma unroll
        for (int r = 0; r < 8; ++r)
            *(u16x8*)(dptr + r * 8) = *(const u16x8*)(sp + r * 8);
    }
}

// ---------------- ctx reduce+normalize: CTXB[bh][e][d] = sum_slots PART / S ----------------
__global__ __launch_bounds__(256) void k_ctxnorm(const float* __restrict__ PART,
                                                 const float* __restrict__ S,
                                                 unsigned short* __restrict__ ctxb) {
    __shared__ float SUM[1024];
    __shared__ float sinv[32];
    const int bh = blockIdx.x, wq = blockIdx.y;
    const int b = bh >> 3, h = bh & 7;
    const int t = threadIdx.x;
    const int bd = (wq >> 1) * 32, be = (wq & 1) * 32;
#pragma unroll
    for (int r = 0; r < 4; ++r) {
        const int kl = t + 256 * r;
        const float* src = PART + (size_t)((b * 32) * 8 + h) * 4096 + wq * 1024 + kl;
        float s = 0.f;
#pragma unroll
        for (int mi = 0; mi < 32; ++mi)
            s += src[(size_t)mi * 8 * 4096];
        SUM[kl] = s;
    }
    if (t < 32) sinv[t] = 1.f / S[bh * 64 + bd + t];
    __syncthreads();
#pragma unroll
    for (int r = 0; r < 4; ++r) {
        const int idx = t + 256 * r;
        const int dd = idx & 31, ee = idx >> 5;
        const int d = bd + dd, e = be + ee;
        const int l2 = (((d >> 2) & 3) << 4) | (e & 15);
        const int i2 = (d >> 4) & 1, j2 = (e >> 4) & 1, q = d & 3;
        const int kl = l2 * 16 + (i2 * 2 + j2) * 4 + q;
        ctxb[(size_t)bh * 4096 + e * 64 + d] = f2bf(SUM[kl] * sinv[dd]);
    }
}

// ---------------- final projection GEMM, 64x128 tiles, K=1024, counted-vmcnt 2-deep ----------------
__global__ __launch_bounds__(256) void k_out_gemm(const __bf16* __restrict__ A,    // CATB [M][1024]
                                                  const __bf16* __restrict__ B,    // WOUT [256][1024]
                                                  float* __restrict__ C,
                                                  const float* __restrict__ bias) {
    __shared__ __align__(16) __bf16 SMEM[24576];   // 48 KB: 2 bufs x (A 4096 + B 8192 elems)
    const int K = 1024;
    const int m0 = blockIdx.x * 64, n0 = blockIdx.y * 128;
    const int t = threadIdx.x;
    const int w = t >> 6, l = t & 63;
    const int wm = (w >> 1) * 32, wn = (w & 1) * 64;
    f32x4 acc[2][4];
#pragma unroll
    for (int i = 0; i < 2; ++i)
#pragma unroll
        for (int j = 0; j < 4; ++j) acc[i][j] = (f32x4){0.f, 0.f, 0.f, 0.f};

    const int lrow = l >> 3;
    const int lchunk = (l & 7) ^ lrow;
    auto STAGE = [&](int buf, int k0) {
        __bf16* As = SMEM + buf * 12288;
        __bf16* Bs = As + 4096;
#pragma unroll
        for (int r = 0; r < 2; ++r) {         // A: 8 stripes (64 rows)
            const int s = w + r * 4;
            const int row = s * 8 + lrow;
            const __bf16* ga = A + (size_t)(m0 + row) * K + (k0 + lchunk * 8);
            __builtin_amdgcn_global_load_lds((const __attribute__((address_space(1))) void*)ga,
                                             (__attribute__((address_space(3))) void*)(As + s * 512),
                                             16, 0, 0);
        }
#pragma unroll
        for (int r = 0; r < 4; ++r) {         // B: 16 stripes (128 rows)
            const int s = w + r * 4;
            const int row = s * 8 + lrow;
            const __bf16* gb = B + (size_t)(n0 + row) * K + (k0 + lchunk * 8);
            __builtin_amdgcn_global_load_lds((const __attribute__((address_space(1))) void*)gb,
                                             (__attribute__((address_space(3))) void*)(Bs + s * 512),
                                             16, 0, 0);
        }
    };

    STAGE(0, 0);
    STAGE(1, 64);
    for (int it = 0; it < 16; ++it) {
        if (it < 15) { asm volatile("s_waitcnt vmcnt(6)" ::: "memory"); }
        else         { asm volatile("s_waitcnt vmcnt(0)" ::: "memory"); }
        __builtin_amdgcn_sched_barrier(0);
        __builtin_amdgcn_s_barrier();
        __builtin_amdgcn_sched_barrier(0);
        const __bf16* As = SMEM + (it & 1) * 12288;
        const __bf16* Bs = As + 4096;
#pragma unroll
        for (int ks = 0; ks < 2; ++ks) {
            const int ac = ((l >> 4) + ks * 4) ^ (l & 7);
            bf16x8 af[2], bfr[4];
#pragma unroll
            for (int i = 0; i < 2; ++i) {
                const int arow = wm + i * 16 + (l & 15);
                af[i] = *(const bf16x8*)(As + arow * 64 + ac * 8);
            }
#pragma unroll
            for (int j = 0; j < 4; ++j) {
                const int brow = wn + j * 16 + (l & 15);
                bfr[j] = *(const bf16x8*)(Bs + brow * 64 + ac * 8);
            }
#pragma unroll
            for (int i = 0; i < 2; ++i)
#pragma unroll
                for (int j = 0; j < 4; ++j)
                    acc[i][j] = __builtin_amdgcn_mfma_f32_16x16x32_bf16(af[i], bfr[j], acc[i][j], 0, 0, 0);
        }
        __builtin_amdgcn_sched_barrier(0);
        __builtin_amdgcn_s_barrier();
        __builtin_amdgcn_sched_barrier(0);
        if (it < 14) STAGE(it & 1, (it + 2) * 64);
    }
    const int b = m0 >> 12;
#pragma unroll
    for (int j = 0; j < 4; ++j) {
        const int col = n0 + wn + j * 16 + (l & 15);
        const float bv = bias[col];
        float* obase = C + ((size_t)(b * 256 + col) << 12);
#pragma unroll
        for (int i = 0; i < 2; ++i) {
            const int rb = (m0 & 4095) + wm + i * 16 + (l >> 4) * 4;
            f32x4 v = acc[i][j];
            v[0] += bv; v[1] += bv; v[2] += bv; v[3] += bv;
            *(f32x4*)(obase + rb) = v;
        }
    }
}

// ---------------- fused: lin_out (MFMA+GELU) and local 3x3 window attention -> CATB ----------------
// blocks [0,1024): lin path (p0=(bid&127)*128, h=bid>>7); blocks [1024,5120): local path.
// LQBT[4][16384][128]: head h at tile h>>1, col (h&1)*64.
// CKV2T[12][16384][128]: q tiles 0..3, k tiles 4..7, v tiles 8..11; head h -> tile h>>1, col (h&1)*64.
__global__ __launch_bounds__(256) void k_linlocal(const __bf16* __restrict__ LQBT,
                                                  const __bf16* __restrict__ ctxb,
                                                  const unsigned short* __restrict__ CKV,
                                                  unsigned short* __restrict__ CAT) {
    const int bid = blockIdx.x;
    const int t = threadIdx.x;
    if (bid < 1024) {
        const int p0 = (bid & 127) * 128;
        const int h  = bid >> 7;
        const int b  = p0 >> 12;
        const int w = t >> 6, l = t & 63;
        const int wm = w * 32;
        const __bf16* Bm = ctxb + (size_t)(b * 8 + h) * 4096;
        const __bf16* Ah = LQBT + ((size_t)(h >> 1) << 21) + (h & 1) * 64;
        f32x4 acc[2][4];
#pragma unroll
        for (int i = 0; i < 2; ++i)
#pragma unroll
            for (int j = 0; j < 4; ++j) acc[i][j] = (f32x4){0.f, 0.f, 0.f, 0.f};
#pragma unroll
        for (int ks = 0; ks < 2; ++ks) {
            const int c = (l >> 4) + ks * 4;
            bf16x8 af[2], bfr[4];
#pragma unroll
            for (int i = 0; i < 2; ++i) {
                const int row = p0 + wm + i * 16 + (l & 15);
                af[i] = *(const bf16x8*)(Ah + (size_t)row * 128 + c * 8);
            }
#pragma unroll
            for (int j = 0; j < 4; ++j) {
                const int erow = j * 16 + (l & 15);
                bfr[j] = *(const bf16x8*)(Bm + erow * 64 + c * 8);
            }
#pragma unroll
            for (int i = 0; i < 2; ++i)
#pragma unroll
                for (int j = 0; j < 4; ++j)
                    acc[i][j] = __builtin_amdgcn_mfma_f32_16x16x32_bf16(af[i], bfr[j], acc[i][j], 0, 0, 0);
        }
#pragma unroll
        for (int i = 0; i < 2; ++i) {
#pragma unroll
            for (int j = 0; j < 4; ++j) {
                const int e = j * 16 + (l & 15);
#pragma unroll
                for (int q = 0; q < 4; ++q) {
                    const int p = p0 + wm + i * 16 + (l >> 4) * 4 + q;
                    float x = acc[i][j][q];
                    float g = 0.5f * x * (1.f + erff(x * 0.70710678118654752f));
                    CAT[(size_t)p * 1024 + h * 64 + e] = f2bf(g);
                }
            }
        }
    } else {
        const int W = (bid - 1024) * 4 + (t >> 6);   // wave id 0..16383
        const int lane = t & 63;
        const int h = W & 7;
        const int G = W >> 3;                 // pixel-group 0..2047
        const int yg = G & 7, x = (G >> 3) & 63, b = G >> 9;
        const int lg = lane >> 3, c8 = lane & 7;
        const int y = (yg << 3) + lg;
        const int p = (b << 12) + (x << 6) + y;
        const unsigned short* Qp = CKV + ((size_t)(h >> 1) << 21) + (size_t)p * 128 + (h & 1) * 64 + c8 * 8;
        const unsigned short* Kp = Qp + ((size_t)4 << 21);
        const unsigned short* Vp = Qp + ((size_t)8 << 21);

        const bool okx[3] = {x > 0, true, x < 63};
        const bool oky[3] = {y > 0, true, y < 63};
        bool okn[9]; int ofs[9];
#pragma unroll
        for (int dx = 0; dx < 3; ++dx)
#pragma unroll
            for (int dy = 0; dy < 3; ++dy) {
                const int k = dx * 3 + dy;
                okn[k] = okx[dx] && oky[dy];
                ofs[k] = okn[k] ? ((dx - 1) * 64 + (dy - 1)) * 128 : 0;   // clamp to self if OOB
            }
        float qf[8];
        {
            u16x8 q8 = *(const u16x8*)Qp;
#pragma unroll
            for (int d = 0; d < 8; ++d) qf[d] = bf2f(q8[d]);
        }
        float sim[9];
#pragma unroll
        for (int k = 0; k < 9; ++k) {
            u16x8 k8 = *(const u16x8*)(Kp + ofs[k]);
            float s = 0.f;
#pragma unroll
            for (int d = 0; d < 8; ++d) s += qf[d] * bf2f(k8[d]);
            s = okn[k] ? s : 0.f;                 // OOB logit contributes exactly 0
            s += __shfl_xor(s, 1);
            s += __shfl_xor(s, 2);
            s += __shfl_xor(s, 4);                // octet all-reduce
            sim[k] = s;
        }
        float mx = sim[0];
#pragma unroll
        for (int k = 1; k < 9; ++k) mx = fmaxf(mx, sim[k]);
        float a[9], Z = 0.f;
#pragma unroll
        for (int k = 0; k < 9; ++k) { a[k] = __expf(sim[k] - mx); Z += a[k]; }
        float inv = 1.f / Z;
#pragma unroll
        for (int k = 0; k < 9; ++k) a[k] = okn[k] ? a[k] * inv : 0.f;   // OOB taps give 0 to PV
        float o[8] = {0.f, 0.f, 0.f, 0.f, 0.f, 0.f, 0.f, 0.f};
#pragma unroll
        for (int k = 0; k < 9; ++k) {
            u16x8 v8 = *(const u16x8*)(Vp + ofs[k]);
#pragma unroll
            for (int d = 0; d < 8; ++d) o[d] += a[k] * bf2f(v8[d]);
        }
        unsigned short* dst = CAT + (size_t)p * 1024 + 512 + h * 64 + c8 * 8;
        uint4 w0;
        w0.x = (unsigned)f2bf(o[0]) | ((unsigned)f2bf(o[1]) << 16);
        w0.y = (unsigned)f2bf(o[2]) | ((unsigned)f2bf(o[3]) << 16);
        w0.z = (unsigned)f2bf(o[4]) | ((unsigned)f2bf(o[5]) << 16);
        w0.w = (unsigned)f2bf(o[6]) | ((unsigned)f2bf(o[7]) << 16);
        *(uint4*)dst = w0;
    }
}

extern "C" void kernel_launch(void* const* d_in, const int* in_sizes, int n_in,
                              void* d_out, int out_size, void* d_ws, size_t ws_size,
                              hipStream_t stream) {
    const float* fmap  = (const float*)d_in[0];
    const float* w_lq  = (const float*)d_in[1];
    const float* w_dw  = (const float*)d_in[2];
    const float* w_pw  = (const float*)d_in[3];
    const float* w_q   = (const float*)d_in[4];
    const float* w_kv  = (const float*)d_in[5];
    const float* w_out = (const float*)d_in[6];
    const float* b_out = (const float*)d_in[7];
    float* out = (float*)d_out;

    // ---- workspace layout (~137 MB, all bf16 except PART/S) ----
    unsigned short* base = (unsigned short*)d_ws;
    unsigned short* CATB = base;                                // [16384][1024]
    unsigned short* FMB  = base + (size_t)NTOT * 1024;          // [16384][256]
    unsigned short* DWB  = FMB + (size_t)NTOT * 256;            // [16384][256]
    unsigned short* WB   = DWB + (size_t)NTOT * 256;            // weights
    unsigned short* WQKV = WB;                                  // [2048][256]
    unsigned short* WPW  = WB + 524288;                         // [1024][256] (head-paired)
    unsigned short* WOUT = WB + 786432;                         // [256][1024]
    unsigned short* CTXB = WB + 1048576;                        // [32][64][64]
    unsigned short* LQBT = CTXB + 131072;                       // [4][16384][128] tile-major
    unsigned short* CKV2T= LQBT + (size_t)NTOT * 512;           // [12][16384][128] tile-major
    float* PART = (float*)(CKV2T + (size_t)NTOT * 1536);        // [128*8][4096] fp32 raw partials
    float* S    = PART + (size_t)1024 * 4096;                   // [2048]

    k_transpose_bf<<<dim3(64, 4, 4), 256, 0, stream>>>(fmap, FMB);
    k_convert_w<<<4096, 256, 0, stream>>>(w_lq, w_q, w_kv, w_pw, w_out, WB);
    hipMemsetAsync(S, 0, 2048 * sizeof(float), stream);
    k_dwconv_bf<<<2048, 256, 0, stream>>>(FMB, w_dw, DWB);
    k_qkv_gemm<<<dim3(128, 24), 256, 0, stream>>>((const __bf16*)FMB, (const __bf16*)DWB,
                                                  (const __bf16*)WQKV, (const __bf16*)WPW,
                                                  LQBT, CKV2T, PART, S);
    k_ctxnorm<<<dim3(32, 4), 256, 0, stream>>>(PART, S, CTXB);
    k_linlocal<<<5120, 256, 0, stream>>>((const __bf16*)LQBT, (const __bf16*)CTXB, CKV2T, CATB);
    k_out_gemm<<<dim3(256, 2), 256, 0, stream>>>((const __bf16*)CATB, (const __bf16*)WOUT, out, b_out);
}

// Round 18
// 159.816 us; speedup vs baseline: 1.0519x; 1.0318x over previous
//
#include <hip/hip_runtime.h>
#include <cmath>

#define NPIX 4096      // 64*64 pixels per image
#define NTOT 16384     // 4 * 4096
#define CIN  256

typedef __bf16 bf16x8 __attribute__((ext_vector_type(8)));
typedef float  f32x4  __attribute__((ext_vector_type(4)));
typedef unsigned short u16x8 __attribute__((ext_vector_type(8)));

static __device__ __forceinline__ unsigned short f2bf(float f) {
    unsigned u = __float_as_uint(f);
    unsigned r = (u + 0x7FFFu + ((u >> 16) & 1u)) >> 16;
    return (unsigned short)r;
}
static __device__ __forceinline__ float bf2f(unsigned short u) {
    return __uint_as_float((unsigned)u << 16);
}

// ---------------- channel-major fp32 [B][256][4096] -> pixel-major bf16 [B*4096][256] ----------------
__global__ __launch_bounds__(256) void k_transpose_bf(const float* __restrict__ src,
                                                      unsigned short* __restrict__ dst) {
    __shared__ float tile[64][65];
    int p0 = blockIdx.x * 64;          // pixel base
    int c0 = blockIdx.y * 64;          // channel base
    int b  = blockIdx.z;
    int t = threadIdx.x;
    int tp = t & 63, tg = t >> 6;      // tg 0..3
    const float* s = src + ((size_t)(b * 256 + c0) * 4096) + p0;
#pragma unroll
    for (int r = 0; r < 16; ++r) {
        int c = r * 4 + tg;
        tile[tp][c] = s[(size_t)c * 4096 + tp];
    }
    __syncthreads();
    unsigned short* d = dst + ((size_t)(b * 4096 + p0)) * 256 + c0;
#pragma unroll
    for (int r = 0; r < 16; ++r) {
        int pr = r * 4 + tg;
        d[(size_t)pr * 256 + tp] = f2bf(tile[pr][tp]);
    }
}

// ---------------- depthwise 3x3 conv on pixel-major bf16: DWB[p][c] = conv(FMB)[p][c] ----------------
__global__ __launch_bounds__(256) void k_dwconv_bf(const unsigned short* __restrict__ FMB,
                                                   const float* __restrict__ wdw,
                                                   unsigned short* __restrict__ DWB) {
    __shared__ float wl[2560];         // [256 c][10] (pad-10 to dodge bank conflicts)
    int t = threadIdx.x;
    for (int i = t; i < 2304; i += 256) wl[(i / 9) * 10 + (i % 9)] = wdw[i];
    __syncthreads();
    int idx = blockIdx.x * 256 + t;    // over NTOT * 32 (8 channels each)
    int cg = idx & 31, p = idx >> 5;
    int xy = p & 4095, x = xy >> 6, y = xy & 63;
    const unsigned short* base = FMB + (size_t)p * 256 + cg * 8;
    float s[8] = {0.f, 0.f, 0.f, 0.f, 0.f, 0.f, 0.f, 0.f};
#pragma unroll
    for (int dx = 0; dx < 3; ++dx) {
        int xx = x + dx - 1;
        if ((unsigned)xx >= 64u) continue;
#pragma unroll
        for (int dy = 0; dy < 3; ++dy) {
            int yy = y + dy - 1;
            if ((unsigned)yy >= 64u) continue;
            u16x8 v = *(const u16x8*)(base + ((dx - 1) * 64 + (dy - 1)) * 256);
#pragma unroll
            for (int d = 0; d < 8; ++d)
                s[d] += bf2f(v[d]) * wl[(cg * 8 + d) * 10 + dx * 3 + dy];
        }
    }
    uint4 w0;
    w0.x = (unsigned)f2bf(s[0]) | ((unsigned)f2bf(s[1]) << 16);
    w0.y = (unsigned)f2bf(s[2]) | ((unsigned)f2bf(s[3]) << 16);
    w0.z = (unsigned)f2bf(s[4]) | ((unsigned)f2bf(s[5]) << 16);
    w0.w = (unsigned)f2bf(s[6]) | ((unsigned)f2bf(s[7]) << 16);
    *(uint4*)(DWB + (size_t)p * 256 + cg * 8) = w0;
}

// ---------------- weights fp32 -> bf16 ----------------
// WQKV[2048][256] = w_lq | w_q | w_kv.  WPW[1024][256] = head-paired (k_h | v_h per 128 rows).
// WOUT[256][1024] = w_out.
__global__ __launch_bounds__(256) void k_convert_w(const float* __restrict__ w1, const float* __restrict__ w2,
                                                   const float* __restrict__ w3, const float* __restrict__ w4,
                                                   const float* __restrict__ w5,
                                                   unsigned short* __restrict__ dst) {
    int i = blockIdx.x * 256 + threadIdx.x;  // 0..1048575
    float v;
    if (i < 131072)       v = w1[i];
    else if (i < 262144)  v = w2[i - 131072];
    else if (i < 524288)  v = w3[i - 262144];
    else if (i < 786432) {
        int elem = i - 524288;
        int rp = elem >> 8, c = elem & 255;
        int h = rp >> 7, wi = rp & 127;
        int srow = (wi < 64) ? (h * 64 + wi) : (512 + h * 64 + (wi - 64));
        v = w4[srow * 256 + c];
    } else                v = w5[i - 786432];
    dst[i] = f2bf(v);
}

// ---------------- merged QKV GEMM, K=256, 128x128 tiles, counted-vmcnt 2-deep pipeline ----------------
// by<16: A=FMB, B=WQKV, n0=by*128. n0<512 -> LQB [M][512] with FUSED head-softmax (*0.125);
//        n0>=512 -> CKV2 [M][1536] cols n0-512 (q cols [512,1024) pre-scaled 0.125).
// by>=16: A=DWB, B=WPW(head-paired), h=by-16: fused ctx partial into PART + tiny S atomics.
__global__ __launch_bounds__(256) void k_qkv_gemm(const __bf16* __restrict__ FMB,
                                                  const __bf16* __restrict__ DWB,
                                                  const __bf16* __restrict__ WQKV,
                                                  const __bf16* __restrict__ WPW,
                                                  unsigned short* __restrict__ LQB,
                                                  unsigned short* __restrict__ CKV2,
                                                  float* __restrict__ PART,
                                                  float* __restrict__ S) {
    __shared__ __align__(16) __bf16 SMEM[32768];   // 64 KB: 2 tile-bufs x (A 8192 + B 8192 elems)
    const int K = 256;
    const int m0 = blockIdx.x * 128;
    const int by = blockIdx.y;
    const bool g2 = (by >= 16);
    const __bf16* A = g2 ? DWB : FMB;
    const __bf16* B = g2 ? WPW : WQKV;
    const int n0 = (g2 ? by - 16 : by) * 128;
    const int t = threadIdx.x;
    const int w = t >> 6, l = t & 63;
    const int wm = (w >> 1) * 64, wn = (w & 1) * 64;
    f32x4 acc[4][4];
#pragma unroll
    for (int i = 0; i < 4; ++i)
#pragma unroll
        for (int j = 0; j < 4; ++j) acc[i][j] = (f32x4){0.f, 0.f, 0.f, 0.f};

    const int lrow = l >> 3;
    const int lchunk = (l & 7) ^ lrow;        // source pre-swizzle; LDS[row][pc]=global[row][pc^(row&7)]
    auto STAGE = [&](int buf, int k0) {
#pragma unroll
        for (int r = 0; r < 4; ++r) {
            const int s = w + r * 4;
            const int row = s * 8 + lrow;
            const __bf16* ga = A + (size_t)(m0 + row) * K + (k0 + lchunk * 8);
            const __bf16* gb = B + (size_t)(n0 + row) * K + (k0 + lchunk * 8);
            __builtin_amdgcn_global_load_lds((const __attribute__((address_space(1))) void*)ga,
                                             (__attribute__((address_space(3))) void*)(SMEM + buf * 16384 + s * 512),
                                             16, 0, 0);
            __builtin_amdgcn_global_load_lds((const __attribute__((address_space(1))) void*)gb,
                                             (__attribute__((address_space(3))) void*)(SMEM + buf * 16384 + 8192 + s * 512),
                                             16, 0, 0);
        }
    };
    STAGE(0, 0);
    STAGE(1, 64);
#pragma unroll
    for (int it = 0; it < 4; ++it) {
        // counted wait: tile it's 8 loads done; tile it+1's 8 stay in flight (never drain mid-loop)
        if (it < 3) { asm volatile("s_waitcnt vmcnt(8)" ::: "memory"); }
        else        { asm volatile("s_waitcnt vmcnt(0)" ::: "memory"); }
        __builtin_amdgcn_sched_barrier(0);
        __builtin_amdgcn_s_barrier();
        __builtin_amdgcn_sched_barrier(0);
        const __bf16* As = SMEM + (it & 1) * 16384;
        const __bf16* Bs = As + 8192;
#pragma unroll
        for (int ks = 0; ks < 2; ++ks) {
            bf16x8 af[4], bfr[4];
#pragma unroll
            for (int i = 0; i < 4; ++i) {
                const int arow = wm + i * 16 + (l & 15);
                const int ac = ((l >> 4) + ks * 4) ^ (l & 7);   // read-side swizzle
                af[i] = *(const bf16x8*)(As + arow * 64 + ac * 8);
                const int brow = wn + i * 16 + (l & 15);
                bfr[i] = *(const bf16x8*)(Bs + brow * 64 + ac * 8);
            }
#pragma unroll
            for (int i = 0; i < 4; ++i)
#pragma unroll
                for (int j = 0; j < 4; ++j)
                    acc[i][j] = __builtin_amdgcn_mfma_f32_16x16x32_bf16(af[i], bfr[j], acc[i][j], 0, 0, 0);
        }
        __builtin_amdgcn_sched_barrier(0);
        __builtin_amdgcn_s_barrier();     // all waves done reading buf (it&1) -> safe to restage
        __builtin_amdgcn_sched_barrier(0);
        if (it < 2) STAGE(it & 1, (it + 2) * 64);
    }

    if (g2) {
        // ---- fused ctx partial: stage [exp(k)|v] col-major ST[col][130], ctx_part = exp(K)^T V ----
        unsigned short* ST = (unsigned short*)SMEM;   // 128*130 shorts = 33.3 KB (aliases tile bufs)
#pragma unroll
        for (int i = 0; i < 4; ++i) {
            const int prow = wm + i * 16 + (l >> 4) * 4;
#pragma unroll
            for (int j = 0; j < 4; ++j) {
                const int col = wn + j * 16 + (l & 15);
#pragma unroll
                for (int q = 0; q < 4; ++q) {
                    float v = acc[i][j][q];
                    ST[col * 130 + prow + q] = f2bf(col < 64 ? __expf(v) : v);
                }
            }
        }
        __syncthreads();
        const int h  = n0 >> 7;               // head
        const int bh = (m0 >> 12) * 8 + h;
        const int dm = (w >> 1) * 32, en = (w & 1) * 32;
        f32x4 c2[2][2];
        f32x4 s2[2];
#pragma unroll
        for (int i = 0; i < 2; ++i) {
            s2[i] = (f32x4){0.f, 0.f, 0.f, 0.f};
#pragma unroll
            for (int j = 0; j < 2; ++j) c2[i][j] = (f32x4){0.f, 0.f, 0.f, 0.f};
        }
        bf16x8 ones;
#pragma unroll
        for (int d = 0; d < 8; ++d) ones[d] = (__bf16)1.0f;
#pragma unroll
        for (int kp = 0; kp < 4; ++kp) {      // 4 chunks of 32 pixels
            bf16x8 af2[2], bv2[2];
#pragma unroll
            for (int i = 0; i < 2; ++i) {
                const int drow = dm + i * 16 + (l & 15);          // d col (0..63)
                af2[i] = *(const bf16x8*)(ST + drow * 130 + kp * 32 + (l >> 4) * 8);
                const int erow = 64 + en + i * 16 + (l & 15);     // v col (64..127)
                bv2[i] = *(const bf16x8*)(ST + erow * 130 + kp * 32 + (l >> 4) * 8);
            }
#pragma unroll
            for (int i = 0; i < 2; ++i)
#pragma unroll
                for (int j = 0; j < 2; ++j)
                    c2[i][j] = __builtin_amdgcn_mfma_f32_16x16x32_bf16(af2[i], bv2[j], c2[i][j], 0, 0, 0);
            if ((w & 1) == 0)
#pragma unroll
                for (int i = 0; i < 2; ++i)
                    s2[i] = __builtin_amdgcn_mfma_f32_16x16x32_bf16(af2[i], ones, s2[i], 0, 0, 0);
        }
        // clean raw-layout partial store (thread-linear, fully coalesced); decode happens in ctxnorm
        float* pp = PART + ((size_t)((m0 >> 7) * 8 + h)) * 4096 + t * 16;
#pragma unroll
        for (int i = 0; i < 2; ++i)
#pragma unroll
            for (int j = 0; j < 2; ++j)
                *(f32x4*)(pp + (i * 2 + j) * 4) = c2[i][j];
        if ((w & 1) == 0 && (l & 15) == 0) {  // tiny S atomics: 64 per block
#pragma unroll
            for (int i = 0; i < 2; ++i)
#pragma unroll
                for (int q = 0; q < 4; ++q)
                    atomicAdd(&S[bh * 64 + dm + i * 16 + (l >> 4) * 4 + q], s2[i][q]);
        }
        return;
    }

    // ---- g1 epilogue: stage bf16 tile row-major (stride 136), write pixel-major ----
    unsigned short* SU = (unsigned short*)SMEM;
#pragma unroll
    for (int i = 0; i < 4; ++i) {
        const int prow = wm + i * 16 + (l >> 4) * 4;
#pragma unroll
        for (int j = 0; j < 4; ++j) {
            const int col = wn + j * 16 + (l & 15);
            const int cglob = n0 + col;
            const float sc = (cglob >= 512 && cglob < 1024) ? 0.125f : 1.f;  // q pre-scaled
#pragma unroll
            for (int q = 0; q < 4; ++q)
                SU[(prow + q) * 136 + col] = f2bf(acc[i][j][q] * sc);
        }
    }
    __syncthreads();
    const int pix = t >> 1, half = t & 1;
    unsigned short* sp = SU + pix * 136 + half * 64;
    if (n0 < 512) {
        // fused lq softmax (single-expf writeback) over this thread's (pixel, head) 64-value slice
        float m = -1e30f;
#pragma unroll
        for (int r = 0; r < 8; ++r) {
            u16x8 v = *(const u16x8*)(sp + r * 8);
#pragma unroll
            for (int d = 0; d < 8; ++d) m = fmaxf(m, bf2f(v[d]));
        }
        float Z = 0.f;
#pragma unroll
        for (int r = 0; r < 8; ++r) {
            u16x8 v = *(const u16x8*)(sp + r * 8);
            u16x8 e;
#pragma unroll
            for (int d = 0; d < 8; ++d) {
                float ev = __expf(bf2f(v[d]) - m);
                Z += ev;
                e[d] = f2bf(ev);
            }
            *(u16x8*)(sp + r * 8) = e;    // thread-private slice, no hazard
        }
        float inv = 0.125f / Z;
        unsigned short* dst = LQB + (size_t)(m0 + pix) * 512 + n0 + half * 64;
#pragma unroll
        for (int r = 0; r < 8; ++r) {
            u16x8 e = *(const u16x8*)(sp + r * 8);
            float o[8];
#pragma unroll
            for (int d = 0; d < 8; ++d) o[d] = bf2f(e[d]) * inv;
            uint4 wv;
            wv.x = (unsigned)f2bf(o[0]) | ((unsigned)f2bf(o[1]) << 16);
            wv.y = (unsigned)f2bf(o[2]) | ((unsigned)f2bf(o[3]) << 16);
            wv.z = (unsigned)f2bf(o[4]) | ((unsigned)f2bf(o[5]) << 16);
            wv.w = (unsigned)f2bf(o[6]) | ((unsigned)f2bf(o[7]) << 16);
            *(uint4*)(dst + r * 8) = wv;
        }
    } else {
        unsigned short* dptr = CKV2 + (size_t)(m0 + pix) * 1536 + (n0 - 512) + half * 64;
#pragma unroll
        for (int r = 0; r < 8; ++r)
            *(u16x8*)(dptr + r * 8) = *(const u16x8*)(sp + r * 8);
    }
}

// ---------------- ctx reduce+normalize: CTXB[bh][e][d] = sum_slots PART / S ----------------
__global__ __launch_bounds__(256) void k_ctxnorm(const float* __restrict__ PART,
                                                 const float* __restrict__ S,
                                                 unsigned short* __restrict__ ctxb) {
    __shared__ float SUM[1024];
    __shared__ float sinv[32];
    const int bh = blockIdx.x, wq = blockIdx.y;
    const int b = bh >> 3, h = bh & 7;
    const int t = threadIdx.x;
    const int bd = (wq >> 1) * 32, be = (wq & 1) * 32;
#pragma unroll
    for (int r = 0; r < 4; ++r) {
        const int kl = t + 256 * r;
        const float* src = PART + (size_t)((b * 32) * 8 + h) * 4096 + wq * 1024 + kl;
        float s = 0.f;
#pragma unroll
        for (int mi = 0; mi < 32; ++mi)
            s += src[(size_t)mi * 8 * 4096];
        SUM[kl] = s;
    }
    if (t < 32) sinv[t] = 1.f / S[bh * 64 + bd + t];
    __syncthreads();
#pragma unroll
    for (int r = 0; r < 4; ++r) {
        const int idx = t + 256 * r;
        const int dd = idx & 31, ee = idx >> 5;
        const int d = bd + dd, e = be + ee;
        const int l2 = (((d >> 2) & 3) << 4) | (e & 15);
        const int i2 = (d >> 4) & 1, j2 = (e >> 4) & 1, q = d & 3;
        const int kl = l2 * 16 + (i2 * 2 + j2) * 4 + q;
        ctxb[(size_t)bh * 4096 + e * 64 + d] = f2bf(SUM[kl] * sinv[dd]);
    }
}

// ---------------- final projection GEMM, 64x128 tiles, K=1024, counted-vmcnt 2-deep ----------------
__global__ __launch_bounds__(256) void k_out_gemm(const __bf16* __restrict__ A,    // CATB [M][1024]
                                                  const __bf16* __restrict__ B,    // WOUT [256][1024]
                                                  float* __restrict__ C,
                                                  const float* __restrict__ bias) {
    __shared__ __align__(16) __bf16 SMEM[24576];   // 48 KB: 2 bufs x (A 4096 + B 8192 elems)
    const int K = 1024;
    const int m0 = blockIdx.x * 64, n0 = blockIdx.y * 128;
    const int t = threadIdx.x;
    const int w = t >> 6, l = t & 63;
    const int wm = (w >> 1) * 32, wn = (w & 1) * 64;
    f32x4 acc[2][4];
#pragma unroll
    for (int i = 0; i < 2; ++i)
#pragma unroll
        for (int j = 0; j < 4; ++j) acc[i][j] = (f32x4){0.f, 0.f, 0.f, 0.f};

    const int lrow = l >> 3;
    const int lchunk = (l & 7) ^ lrow;
    auto STAGE = [&](int buf, int k0) {
        __bf16* As = SMEM + buf * 12288;
        __bf16* Bs = As + 4096;
#pragma unroll
        for (int r = 0; r < 2; ++r) {         // A: 8 stripes (64 rows)
            const int s = w + r * 4;
            const int row = s * 8 + lrow;
            const __bf16* ga = A + (size_t)(m0 + row) * K + (k0 + lchunk * 8);
            __builtin_amdgcn_global_load_lds((const __attribute__((address_space(1))) void*)ga,
                                             (__attribute__((address_space(3))) void*)(As + s * 512),
                                             16, 0, 0);
        }
#pragma unroll
        for (int r = 0; r < 4; ++r) {         // B: 16 stripes (128 rows)
            const int s = w + r * 4;
            const int row = s * 8 + lrow;
            const __bf16* gb = B + (size_t)(n0 + row) * K + (k0 + lchunk * 8);
            __builtin_amdgcn_global_load_lds((const __attribute__((address_space(1))) void*)gb,
                                             (__attribute__((address_space(3))) void*)(Bs + s * 512),
                                             16, 0, 0);
        }
    };

    STAGE(0, 0);
    STAGE(1, 64);
    for (int it = 0; it < 16; ++it) {
        if (it < 15) { asm volatile("s_waitcnt vmcnt(6)" ::: "memory"); }
        else         { asm volatile("s_waitcnt vmcnt(0)" ::: "memory"); }
        __builtin_amdgcn_sched_barrier(0);
        __builtin_amdgcn_s_barrier();
        __builtin_amdgcn_sched_barrier(0);
        const __bf16* As = SMEM + (it & 1) * 12288;
        const __bf16* Bs = As + 4096;
#pragma unroll
        for (int ks = 0; ks < 2; ++ks) {
            const int ac = ((l >> 4) + ks * 4) ^ (l & 7);
            bf16x8 af[2], bfr[4];
#pragma unroll
            for (int i = 0; i < 2; ++i) {
                const int arow = wm + i * 16 + (l & 15);
                af[i] = *(const bf16x8*)(As + arow * 64 + ac * 8);
            }
#pragma unroll
            for (int j = 0; j < 4; ++j) {
                const int brow = wn + j * 16 + (l & 15);
                bfr[j] = *(const bf16x8*)(Bs + brow * 64 + ac * 8);
            }
#pragma unroll
            for (int i = 0; i < 2; ++i)
#pragma unroll
                for (int j = 0; j < 4; ++j)
                    acc[i][j] = __builtin_amdgcn_mfma_f32_16x16x32_bf16(af[i], bfr[j], acc[i][j], 0, 0, 0);
        }
        __builtin_amdgcn_sched_barrier(0);
        __builtin_amdgcn_s_barrier();
        __builtin_amdgcn_sched_barrier(0);
        if (it < 14) STAGE(it & 1, (it + 2) * 64);
    }
    const int b = m0 >> 12;
#pragma unroll
    for (int j = 0; j < 4; ++j) {
        const int col = n0 + wn + j * 16 + (l & 15);
        const float bv = bias[col];
        float* obase = C + ((size_t)(b * 256 + col) << 12);
#pragma unroll
        for (int i = 0; i < 2; ++i) {
            const int rb = (m0 & 4095) + wm + i * 16 + (l >> 4) * 4;
            f32x4 v = acc[i][j];
            v[0] += bv; v[1] += bv; v[2] += bv; v[3] += bv;
            *(f32x4*)(obase + rb) = v;
        }
    }
}

// ---------------- fused: lin_out (MFMA+GELU) and local 3x3 window attention -> CATB ----------------
// blocks [0,1024): lin path (p0=(bid&127)*128, h=bid>>7); blocks [1024,5120): local path.
__global__ __launch_bounds__(256) void k_linlocal(const __bf16* __restrict__ LQB,
                                                  const __bf16* __restrict__ ctxb,
                                                  const unsigned short* __restrict__ CKV,
                                                  unsigned short* __restrict__ CAT) {
    const int bid = blockIdx.x;
    const int t = threadIdx.x;
    if (bid < 1024) {
        const int p0 = (bid & 127) * 128;
        const int h  = bid >> 7;
        const int b  = p0 >> 12;
        const int w = t >> 6, l = t & 63;
        const int wm = w * 32;
        const __bf16* Bm = ctxb + (size_t)(b * 8 + h) * 4096;
        f32x4 acc[2][4];
#pragma unroll
        for (int i = 0; i < 2; ++i)
#pragma unroll
            for (int j = 0; j < 4; ++j) acc[i][j] = (f32x4){0.f, 0.f, 0.f, 0.f};
#pragma unroll
        for (int ks = 0; ks < 2; ++ks) {
            const int c = (l >> 4) + ks * 4;
            bf16x8 af[2], bfr[4];
#pragma unroll
            for (int i = 0; i < 2; ++i) {
                const int row = p0 + wm + i * 16 + (l & 15);
                af[i] = *(const bf16x8*)(LQB + (size_t)row * 512 + h * 64 + c * 8);
            }
#pragma unroll
            for (int j = 0; j < 4; ++j) {
                const int erow = j * 16 + (l & 15);
                bfr[j] = *(const bf16x8*)(Bm + erow * 64 + c * 8);
            }
#pragma unroll
            for (int i = 0; i < 2; ++i)
#pragma unroll
                for (int j = 0; j < 4; ++j)
                    acc[i][j] = __builtin_amdgcn_mfma_f32_16x16x32_bf16(af[i], bfr[j], acc[i][j], 0, 0, 0);
        }
#pragma unroll
        for (int i = 0; i < 2; ++i) {
#pragma unroll
            for (int j = 0; j < 4; ++j) {
                const int e = j * 16 + (l & 15);
#pragma unroll
                for (int q = 0; q < 4; ++q) {
                    const int p = p0 + wm + i * 16 + (l >> 4) * 4 + q;
                    float x = acc[i][j][q];
                    float g = 0.5f * x * (1.f + erff(x * 0.70710678118654752f));
                    CAT[(size_t)p * 1024 + h * 64 + e] = f2bf(g);
                }
            }
        }
    } else {
        const int W = (bid - 1024) * 4 + (t >> 6);   // wave id 0..16383
        const int lane = t & 63;
        const int h = W & 7;
        const int G = W >> 3;                 // pixel-group 0..2047
        const int yg = G & 7, x = (G >> 3) & 63, b = G >> 9;
        const int lg = lane >> 3, c8 = lane & 7;
        const int y = (yg << 3) + lg;
        const int p = (b << 12) + (x << 6) + y;
        const unsigned short* Qp = CKV + (size_t)p * 1536 + h * 64 + c8 * 8;
        const unsigned short* Kp = Qp + 512;
        const unsigned short* Vp = Qp + 1024;

        const bool okx[3] = {x > 0, true, x < 63};
        const bool oky[3] = {y > 0, true, y < 63};
        bool okn[9]; int ofs[9];
#pragma unroll
        for (int dx = 0; dx < 3; ++dx)
#pragma unroll
            for (int dy = 0; dy < 3; ++dy) {
                const int k = dx * 3 + dy;
                okn[k] = okx[dx] && oky[dy];
                ofs[k] = okn[k] ? ((dx - 1) * 64 + (dy - 1)) * 1536 : 0;   // clamp to self if OOB
            }
        float qf[8];
        {
            u16x8 q8 = *(const u16x8*)Qp;
#pragma unroll
            for (int d = 0; d < 8; ++d) qf[d] = bf2f(q8[d]);
        }
        float sim[9];
#pragma unroll
        for (int k = 0; k < 9; ++k) {
            u16x8 k8 = *(const u16x8*)(Kp + ofs[k]);
            float s = 0.f;
#pragma unroll
            for (int d = 0; d < 8; ++d) s += qf[d] * bf2f(k8[d]);
            s = okn[k] ? s : 0.f;                 // OOB logit contributes exactly 0
            s += __shfl_xor(s, 1);
            s += __shfl_xor(s, 2);
            s += __shfl_xor(s, 4);                // octet all-reduce
            sim[k] = s;
        }
        float mx = sim[0];
#pragma unroll
        for (int k = 1; k < 9; ++k) mx = fmaxf(mx, sim[k]);
        float a[9], Z = 0.f;
#pragma unroll
        for (int k = 0; k < 9; ++k) { a[k] = __expf(sim[k] - mx); Z += a[k]; }
        float inv = 1.f / Z;
#pragma unroll
        for (int k = 0; k < 9; ++k) a[k] = okn[k] ? a[k] * inv : 0.f;   // OOB taps give 0 to PV
        float o[8] = {0.f, 0.f, 0.f, 0.f, 0.f, 0.f, 0.f, 0.f};
#pragma unroll
        for (int k = 0; k < 9; ++k) {
            u16x8 v8 = *(const u16x8*)(Vp + ofs[k]);
#pragma unroll
            for (int d = 0; d < 8; ++d) o[d] += a[k] * bf2f(v8[d]);
        }
        unsigned short* dst = CAT + (size_t)p * 1024 + 512 + h * 64 + c8 * 8;
        uint4 w0;
        w0.x = (unsigned)f2bf(o[0]) | ((unsigned)f2bf(o[1]) << 16);
        w0.y = (unsigned)f2bf(o[2]) | ((unsigned)f2bf(o[3]) << 16);
        w0.z = (unsigned)f2bf(o[4]) | ((unsigned)f2bf(o[5]) << 16);
        w0.w = (unsigned)f2bf(o[6]) | ((unsigned)f2bf(o[7]) << 16);
        *(uint4*)dst = w0;
    }
}

extern "C" void kernel_launch(void* const* d_in, const int* in_sizes, int n_in,
                              void* d_out, int out_size, void* d_ws, size_t ws_size,
                              hipStream_t stream) {
    const float* fmap  = (const float*)d_in[0];
    const float* w_lq  = (const float*)d_in[1];
    const float* w_dw  = (const float*)d_in[2];
    const float* w_pw  = (const float*)d_in[3];
    const float* w_q   = (const float*)d_in[4];
    const float* w_kv  = (const float*)d_in[5];
    const float* w_out = (const float*)d_in[6];
    const float* b_out = (const float*)d_in[7];
    float* out = (float*)d_out;

    // ---- workspace layout (~137 MB, all bf16 except PART/S) ----
    unsigned short* base = (unsigned short*)d_ws;
    unsigned short* CATB = base;                                // [16384][1024]
    unsigned short* FMB  = base + (size_t)NTOT * 1024;          // [16384][256]
    unsigned short* DWB  = FMB + (size_t)NTOT * 256;            // [16384][256]
    unsigned short* WB   = DWB + (size_t)NTOT * 256;            // weights
    unsigned short* WQKV = WB;                                  // [2048][256]
    unsigned short* WPW  = WB + 524288;                         // [1024][256] (head-paired)
    unsigned short* WOUT = WB + 786432;                         // [256][1024]
    unsigned short* CTXB = WB + 1048576;                        // [32][64][64]
    unsigned short* LQB  = CTXB + 131072;                       // [16384][512]
    unsigned short* CKV2 = LQB + (size_t)NTOT * 512;            // [16384][1536] (q*s|k|v)
    float* PART = (float*)(CKV2 + (size_t)NTOT * 1536);         // [128*8][4096] fp32 raw partials
    float* S    = PART + (size_t)1024 * 4096;                   // [2048]

    k_transpose_bf<<<dim3(64, 4, 4), 256, 0, stream>>>(fmap, FMB);
    k_convert_w<<<4096, 256, 0, stream>>>(w_lq, w_q, w_kv, w_pw, w_out, WB);
    hipMemsetAsync(S, 0, 2048 * sizeof(float), stream);
    k_dwconv_bf<<<2048, 256, 0, stream>>>(FMB, w_dw, DWB);
    k_qkv_gemm<<<dim3(128, 24), 256, 0, stream>>>((const __bf16*)FMB, (const __bf16*)DWB,
                                                  (const __bf16*)WQKV, (const __bf16*)WPW,
                                                  LQB, CKV2, PART, S);
    k_ctxnorm<<<dim3(32, 4), 256, 0, stream>>>(PART, S, CTXB);
    k_linlocal<<<5120, 256, 0, stream>>>((const __bf16*)LQB, (const __bf16*)CTXB, CKV2, CATB);
    k_out_gemm<<<dim3(256, 2), 256, 0, stream>>>((const __bf16*)CATB, (const __bf16*)WOUT, out, b_out);
}